// Round 1
// baseline (12071.671 us; speedup 1.0000x reference)
//
#include <hip/hip_runtime.h>
#include <math.h>

#define EDGES 120000
#define NN    30000

__device__ __forceinline__ float sigmoidf_(float x) { return 1.f / (1.f + __expf(-x)); }

// ---------------- degree / norm ----------------
__global__ void count_kernel(const int* __restrict__ src, const int* __restrict__ dst,
                             int* __restrict__ deg_out, int* __restrict__ deg_in) {
  int j = blockIdx.x * blockDim.x + threadIdx.x;
  if (j >= EDGES) return;
  atomicAdd(&deg_out[src[j]], 1);
  atomicAdd(&deg_in[dst[j]], 1);
}

__global__ void norm_kernel(const int* __restrict__ src, const int* __restrict__ dst,
                            const int* __restrict__ deg_out, const int* __restrict__ deg_in,
                            float* __restrict__ norm) {
  int j = blockIdx.x * blockDim.x + threadIdx.x;
  if (j >= EDGES) return;
  int dout = deg_out[src[j]]; if (dout < 1) dout = 1;
  int din  = deg_in[dst[j]];  if (din  < 1) din  = 1;
  norm[j] = rsqrtf((float)dout) * rsqrtf((float)din);
}

// ---------------- block1 temporal GLU conv: x[B,N,6,1] -> X1[N][64][8] ----------------
__global__ void glu1_kernel(const float* __restrict__ x, const float* __restrict__ w,
                            const float* __restrict__ b, float* __restrict__ X1) {
  int idx = blockIdx.x * blockDim.x + threadIdx.x;   // idx = n*64 + s, s = b*4 + t
  if (idx >= NN * 64) return;
  int n = idx >> 6, s = idx & 63;
  int bb = s >> 2, t = s & 3;
  const float* xb = x + ((long)bb * NN + n) * 6;
  float x0 = xb[t], x1 = xb[t + 1], x2 = xb[t + 2];
  float* o = X1 + (long)idx * 8;
#pragma unroll
  for (int c = 0; c < 8; ++c) {
    float p = w[c * 3 + 0] * x0 + w[c * 3 + 1] * x1 + w[c * 3 + 2] * x2 + b[c];
    float q = w[(c + 8) * 3 + 0] * x0 + w[(c + 8) * 3 + 1] * x1 + w[(c + 8) * 3 + 2] * x2 + b[c + 8];
    float al = (c == 0) ? x2 : 0.f;
    o[c] = (p + al) * sigmoidf_(q);
  }
}

// ---------------- edge scatter: out[dst] += mult * norm * in[src]  (rows of CH float4s) ----------------
template <int CH>
__global__ void scatter_kernel(const int* __restrict__ src, const int* __restrict__ dst,
                               const float* __restrict__ norm, const float* __restrict__ in,
                               float* __restrict__ out, float mult) {
  int tid = blockIdx.x * blockDim.x + threadIdx.x;
  if (tid >= EDGES * CH) return;
  int e = tid / CH, j = tid - e * CH;
  float nm = norm[e] * mult;
  float4 v = reinterpret_cast<const float4*>(in)[src[e] * CH + j];
  float* o = out + ((long)dst[e] * CH + j) * 4;
  unsafeAtomicAdd(o + 0, nm * v.x);
  unsafeAtomicAdd(o + 1, nm * v.y);
  unsafeAtomicAdd(o + 2, nm * v.z);
  unsafeAtomicAdd(o + 3, nm * v.w);
}

// ---------------- per-node Chebyshev combine: out[:,choff:choff+C] += T0*(W0-W2) + T1*W1 + T2s*W2 + bias ----------------
template <int C, int S, int OSTR>
__global__ void accum_kernel(const float* __restrict__ X, const float* __restrict__ T1,
                             const float* __restrict__ T2, const float* __restrict__ W,
                             const float* __restrict__ bias, float* __restrict__ out, int choff) {
  __shared__ float w0[C * C], w1[C * C], w2[C * C], bb[C];
  for (int i = threadIdx.x; i < C * C; i += blockDim.x) {
    w0[i] = W[i] - W[2 * C * C + i];
    w1[i] = W[C * C + i];
    w2[i] = W[2 * C * C + i];
  }
  if (threadIdx.x < C) bb[threadIdx.x] = bias[threadIdx.x];
  __syncthreads();
  int idx = blockIdx.x * blockDim.x + threadIdx.x;
  if (idx >= NN * S) return;
  float xr[C], t1r[C], t2r[C];
  long base = (long)idx * C;
#pragma unroll
  for (int c = 0; c < C; ++c) { xr[c] = X[base + c]; t1r[c] = T1[base + c]; t2r[c] = T2[base + c]; }
  float* o = out + (long)idx * OSTR + choff;
#pragma unroll
  for (int d = 0; d < C; ++d) {
    float z = bb[d];
#pragma unroll
    for (int c = 0; c < C; ++c)
      z += xr[c] * w0[c * C + d] + t1r[c] * w1[c * C + d] + t2r[c] * w2[c * C + d];
    o[d] += z;
  }
}

// ---------------- block2 align(1x1) + temporal GLU conv: X2in[N][64][16] -> X2n[N][32][11] ----------------
__global__ void glu2_kernel(const float* __restrict__ X2in, const float* __restrict__ w2,
                            const float* __restrict__ b2, const float* __restrict__ aw,
                            const float* __restrict__ ab, float* __restrict__ X2n) {
  __shared__ float w2s[22 * 16 * 3], b2s[22], aws[11 * 16], abs_[11];
  for (int i = threadIdx.x; i < 22 * 16 * 3; i += blockDim.x) w2s[i] = w2[i];
  if (threadIdx.x < 22) b2s[threadIdx.x] = b2[threadIdx.x];
  for (int i = threadIdx.x; i < 11 * 16; i += blockDim.x) aws[i] = aw[i];
  if (threadIdx.x < 11) abs_[threadIdx.x] = ab[threadIdx.x];
  __syncthreads();
  int idx = blockIdx.x * blockDim.x + threadIdx.x;   // idx = n*32 + s2, s2 = b*2 + t
  if (idx >= NN * 32) return;
  int n = idx >> 5, s = idx & 31;
  int bb = s >> 1, t = s & 1;
  const float* r = X2in + ((long)n * 64 + bb * 4 + t) * 16;  // 3 consecutive time rows of 16 ch
  float xr[48];
#pragma unroll
  for (int i = 0; i < 48; ++i) xr[i] = r[i];
  float* o = X2n + (long)idx * 11;
#pragma unroll
  for (int co = 0; co < 11; ++co) {
    float p = b2s[co], q = b2s[co + 11], a = abs_[co];
#pragma unroll
    for (int ci = 0; ci < 16; ++ci) {
      p += w2s[(co * 16 + ci) * 3 + 0] * xr[ci] + w2s[(co * 16 + ci) * 3 + 1] * xr[16 + ci] +
           w2s[(co * 16 + ci) * 3 + 2] * xr[32 + ci];
      q += w2s[((co + 11) * 16 + ci) * 3 + 0] * xr[ci] + w2s[((co + 11) * 16 + ci) * 3 + 1] * xr[16 + ci] +
           w2s[((co + 11) * 16 + ci) * 3 + 2] * xr[32 + ci];
      a += aws[co * 16 + ci] * xr[32 + ci];
    }
    o[co] = (p + a) * sigmoidf_(q);
  }
}

// ---------------- final: out[b,n,:] = z[b,n,:44] @ W[44,128] + bias ----------------
__global__ __launch_bounds__(128) void final_kernel(const float* __restrict__ X3,
                                                    const float* __restrict__ W,
                                                    const float* __restrict__ bias,
                                                    float* __restrict__ out, int rows) {
  __shared__ float Wl[44 * 128];
  __shared__ float zs[44];
  int tid = threadIdx.x;
  for (int i = tid; i < 44 * 128; i += 128) Wl[i] = W[i];
  float bh = bias[tid];
  for (int r = blockIdx.x; r < rows; r += gridDim.x) {
    __syncthreads();
    if (tid < 44) {
      int c = tid >> 1, t = tid & 1;
      int b = r / NN, n = r - b * NN;
      zs[tid] = X3[((long)n * 32 + b * 2 + t) * 22 + c];
    }
    __syncthreads();
    float acc = bh;
#pragma unroll
    for (int k = 0; k < 44; ++k) acc += zs[k] * Wl[k * 128 + tid];
    out[(long)r * 128 + tid] = acc;
  }
}

// ---------------- host-side ChebConv driver ----------------
template <int C, int S, int OSTR, int CH>
static void run_cheb(const int* edges, const float* nAll, const float* W, const float* bias,
                     const float* Xn, float* T1, float* T2, float* out, int choff,
                     hipStream_t stream) {
  constexpr size_t RB = (size_t)NN * S * C * sizeof(float);
  for (int e = 0; e < 2; ++e) {
    const int* src = edges + (size_t)(2 * e) * EDGES;
    const int* dst = src + EDGES;
    const float* nb = nAll + (size_t)e * EDGES;
    hipMemsetAsync(T1, 0, RB, stream);
    scatter_kernel<CH><<<EDGES * CH / 256, 256, 0, stream>>>(src, dst, nb, Xn, T1, -1.f);
    hipMemsetAsync(T2, 0, RB, stream);
    scatter_kernel<CH><<<EDGES * CH / 256, 256, 0, stream>>>(src, dst, nb, T1, T2, -2.f);
    accum_kernel<C, S, OSTR><<<NN * S / 256, 256, 0, stream>>>(Xn, T1, T2, W + (size_t)e * 3 * C * C,
                                                               bias + (size_t)e * C, out, choff);
  }
}

extern "C" void kernel_launch(void* const* d_in, const int* in_sizes, int n_in,
                              void* d_out, int out_size, void* d_ws, size_t ws_size,
                              hipStream_t stream) {
  const float* x    = (const float*)d_in[0];
  const int*   hg   = (const int*)d_in[1];
  const int*   tg   = (const int*)d_in[2];
  const float* t1w  = (const float*)d_in[3];
  const float* t1b  = (const float*)d_in[4];
  const float* h1W  = (const float*)d_in[5];
  const float* h1b  = (const float*)d_in[6];
  const float* g1W  = (const float*)d_in[7];
  const float* g1b  = (const float*)d_in[8];
  const float* a2w  = (const float*)d_in[9];
  const float* a2b  = (const float*)d_in[10];
  const float* t2w  = (const float*)d_in[11];
  const float* t2b  = (const float*)d_in[12];
  const float* h2W  = (const float*)d_in[13];
  const float* h2b  = (const float*)d_in[14];
  const float* g2W  = (const float*)d_in[15];
  const float* g2b  = (const float*)d_in[16];
  const float* outw = (const float*)d_in[17];
  const float* outb = (const float*)d_in[18];
  float* out = (float*)d_out;

  // workspace layout (floats)
  float* ws = (float*)d_ws;
  float* A  = ws;                        // 15,360,000  X1 [N][64][8]  -> later X2n [N][32][11]
  float* Bf = A + 15360000;              // 15,360,000  T1
  float* Cf = Bf + 15360000;             // 15,360,000  T2
  float* D  = Cf + 15360000;             // 30,720,000  X2in [N][64][16] -> later X3 [N][32][22]
  float* normAll = D + 30720000;         // 480,000 (4 x EDGES)
  int*   deg     = (int*)(normAll + 480000);  // 60,000 ints

  // --- degrees & norms for all 4 edge lists (reused by both blocks) ---
  const int* glist[2] = {hg, tg};
  for (int g = 0; g < 2; ++g)
    for (int e = 0; e < 2; ++e) {
      const int* src = glist[g] + (size_t)(2 * e) * EDGES;
      const int* dst = src + EDGES;
      float* nb = normAll + (size_t)(g * 2 + e) * EDGES;
      hipMemsetAsync(deg, 0, 2 * NN * sizeof(int), stream);
      count_kernel<<<(EDGES + 255) / 256, 256, 0, stream>>>(src, dst, deg, deg + NN);
      norm_kernel<<<(EDGES + 255) / 256, 256, 0, stream>>>(src, dst, deg, deg + NN, nb);
    }

  // --- block1 temporal GLU ---
  glu1_kernel<<<NN * 64 / 256, 256, 0, stream>>>(x, t1w, t1b, A);

  // --- block1 hetcheb (hg -> ch 0..7, tg -> ch 8..15 of X2in) ---
  hipMemsetAsync(D, 0, (size_t)NN * 64 * 16 * sizeof(float), stream);
  run_cheb<8, 64, 16, 128>(hg, normAll, h1W, h1b, A, Bf, Cf, D, 0, stream);
  run_cheb<8, 64, 16, 128>(tg, normAll + 2 * EDGES, g1W, g1b, A, Bf, Cf, D, 8, stream);

  // --- block2 align + temporal GLU: D (X2in) -> A (X2n) ---
  glu2_kernel<<<NN * 32 / 256, 256, 0, stream>>>(D, t2w, t2b, a2w, a2b, A);

  // --- block2 hetcheb (hg -> ch 0..10, tg -> ch 11..21 of X3=D) ---
  hipMemsetAsync(D, 0, (size_t)NN * 32 * 22 * sizeof(float), stream);
  run_cheb<11, 32, 22, 88>(hg, normAll, h2W, h2b, A, Bf, Cf, D, 0, stream);
  run_cheb<11, 32, 22, 88>(tg, normAll + 2 * EDGES, g2W, g2b, A, Bf, Cf, D, 11, stream);

  // --- final linear ---
  final_kernel<<<2048, 128, 0, stream>>>(D, outw, outb, out, 16 * NN);
}

// Round 2
// 1964.634 us; speedup vs baseline: 6.1445x; 6.1445x over previous
//
#include <hip/hip_runtime.h>
#include <math.h>

#define EDGES 120000
#define NN    30000

__device__ __forceinline__ float sigmoidf_(float x) { return 1.f / (1.f + __expf(-x)); }

// ---------------- degree count ----------------
__global__ void count_kernel(const int* __restrict__ src, const int* __restrict__ dst,
                             int* __restrict__ deg_out, int* __restrict__ deg_in) {
  int j = blockIdx.x * blockDim.x + threadIdx.x;
  if (j >= EDGES) return;
  atomicAdd(&deg_out[src[j]], 1);
  atomicAdd(&deg_in[dst[j]], 1);
}

// ---------------- exclusive prefix sum of deg_in -> rowptr[N+1] (single block) ----------------
__global__ __launch_bounds__(1024) void scan_kernel(const int* __restrict__ deg, int* __restrict__ rowptr) {
  __shared__ int buf[1024];
  __shared__ int carry;
  int tid = threadIdx.x;
  if (tid == 0) { carry = 0; rowptr[0] = 0; }
  __syncthreads();
  for (int base = 0; base < NN; base += 1024) {
    int v = (base + tid < NN) ? deg[base + tid] : 0;
    buf[tid] = v;
    __syncthreads();
    for (int off = 1; off < 1024; off <<= 1) {
      int t = (tid >= off) ? buf[tid - off] : 0;
      __syncthreads();
      buf[tid] += t;
      __syncthreads();
    }
    if (base + tid < NN) rowptr[base + tid + 1] = carry + buf[tid];
    __syncthreads();
    if (tid == 0) carry += buf[1023];
    __syncthreads();
  }
}

__global__ void cursor_init_kernel(const int* __restrict__ rowptr, int* __restrict__ cursor) {
  int n = blockIdx.x * blockDim.x + threadIdx.x;
  if (n < NN) cursor[n] = rowptr[n];
}

// ---------------- CSR fill (also computes edge norm) ----------------
__global__ void fill_kernel(const int* __restrict__ src, const int* __restrict__ dst,
                            const int* __restrict__ deg_out, const int* __restrict__ deg_in,
                            int* __restrict__ cursor, int* __restrict__ csr_src,
                            float* __restrict__ csr_norm) {
  int j = blockIdx.x * blockDim.x + threadIdx.x;
  if (j >= EDGES) return;
  int s = src[j], d = dst[j];
  float nm = rsqrtf((float)deg_out[s]) * rsqrtf((float)deg_in[d]);
  int p = atomicAdd(&cursor[d], 1);
  csr_src[p] = s;
  csr_norm[p] = nm;
}

// ---------------- block1 temporal GLU conv: x[B,N,6,1] -> X1[N][64][8] ----------------
__global__ void glu1_kernel(const float* __restrict__ x, const float* __restrict__ w,
                            const float* __restrict__ b, float* __restrict__ X1) {
  int idx = blockIdx.x * blockDim.x + threadIdx.x;   // idx = n*64 + s, s = b*4 + t
  if (idx >= NN * 64) return;
  int n = idx >> 6, s = idx & 63;
  int bb = s >> 2, t = s & 3;
  const float* xb = x + ((long)bb * NN + n) * 6;
  float x0 = xb[t], x1 = xb[t + 1], x2 = xb[t + 2];
  float* o = X1 + (long)idx * 8;
#pragma unroll
  for (int c = 0; c < 8; ++c) {
    float p = w[c * 3 + 0] * x0 + w[c * 3 + 1] * x1 + w[c * 3 + 2] * x2 + b[c];
    float q = w[(c + 8) * 3 + 0] * x0 + w[(c + 8) * 3 + 1] * x1 + w[(c + 8) * 3 + 2] * x2 + b[c + 8];
    float al = (c == 0) ? x2 : 0.f;
    o[c] = (p + al) * sigmoidf_(q);
  }
}

// ---------------- CSR pull: out[n] = mult * sum_e norm[e] * in[csrc[e]]  (rows of CHF4 float4) ----------------
template <int CHF4>
__global__ void pull_kernel(const int* __restrict__ rowptr, const int* __restrict__ csrc,
                            const float* __restrict__ cnorm, const float* __restrict__ in,
                            float* __restrict__ out, float mult) {
  int tid = blockIdx.x * blockDim.x + threadIdx.x;
  if (tid >= NN * CHF4) return;
  int n = tid / CHF4, j = tid - n * CHF4;
  const float4* in4 = reinterpret_cast<const float4*>(in);
  float ax = 0.f, ay = 0.f, az = 0.f, aw = 0.f;
  int beg = rowptr[n], end = rowptr[n + 1];
  for (int e = beg; e < end; ++e) {
    float nm = cnorm[e];
    float4 v = in4[(long)csrc[e] * CHF4 + j];
    ax += nm * v.x; ay += nm * v.y; az += nm * v.z; aw += nm * v.w;
  }
  float4 o; o.x = mult * ax; o.y = mult * ay; o.z = mult * az; o.w = mult * aw;
  reinterpret_cast<float4*>(out)[tid] = o;
}

// ---------------- per-node Chebyshev combine: out[:,choff..] (=|+=) T0*(W0-W2) + T1*W1 + T2s*W2 + bias ----------------
template <int C, int S, int OSTR, bool ADD>
__global__ void accum_kernel(const float* __restrict__ X, const float* __restrict__ T1,
                             const float* __restrict__ T2, const float* __restrict__ W,
                             const float* __restrict__ bias, float* __restrict__ out, int choff) {
  __shared__ float w0[C * C], w1[C * C], w2[C * C], bb[C];
  for (int i = threadIdx.x; i < C * C; i += blockDim.x) {
    w0[i] = W[i] - W[2 * C * C + i];
    w1[i] = W[C * C + i];
    w2[i] = W[2 * C * C + i];
  }
  if (threadIdx.x < C) bb[threadIdx.x] = bias[threadIdx.x];
  __syncthreads();
  int idx = blockIdx.x * blockDim.x + threadIdx.x;
  if (idx >= NN * S) return;
  float xr[C], t1r[C], t2r[C];
  long base = (long)idx * C;
#pragma unroll
  for (int c = 0; c < C; ++c) { xr[c] = X[base + c]; t1r[c] = T1[base + c]; t2r[c] = T2[base + c]; }
  float* o = out + (long)idx * OSTR + choff;
#pragma unroll
  for (int d = 0; d < C; ++d) {
    float z = bb[d];
#pragma unroll
    for (int c = 0; c < C; ++c)
      z += xr[c] * w0[c * C + d] + t1r[c] * w1[c * C + d] + t2r[c] * w2[c * C + d];
    if (ADD) o[d] += z; else o[d] = z;
  }
}

// ---------------- block2 align(1x1) + temporal GLU conv: X2in[N][64][16] -> X2n[N][32][11] ----------------
__global__ void glu2_kernel(const float* __restrict__ X2in, const float* __restrict__ w2,
                            const float* __restrict__ b2, const float* __restrict__ aw,
                            const float* __restrict__ ab, float* __restrict__ X2n) {
  __shared__ float w2s[22 * 16 * 3], b2s[22], aws[11 * 16], abs_[11];
  for (int i = threadIdx.x; i < 22 * 16 * 3; i += blockDim.x) w2s[i] = w2[i];
  if (threadIdx.x < 22) b2s[threadIdx.x] = b2[threadIdx.x];
  for (int i = threadIdx.x; i < 11 * 16; i += blockDim.x) aws[i] = aw[i];
  if (threadIdx.x < 11) abs_[threadIdx.x] = ab[threadIdx.x];
  __syncthreads();
  int idx = blockIdx.x * blockDim.x + threadIdx.x;   // idx = n*32 + s2, s2 = b*2 + t
  if (idx >= NN * 32) return;
  int n = idx >> 5, s = idx & 31;
  int bb = s >> 1, t = s & 1;
  const float* r = X2in + ((long)n * 64 + bb * 4 + t) * 16;  // 3 consecutive time rows of 16 ch
  float xr[48];
#pragma unroll
  for (int i = 0; i < 48; ++i) xr[i] = r[i];
  float* o = X2n + (long)idx * 11;
#pragma unroll
  for (int co = 0; co < 11; ++co) {
    float p = b2s[co], q = b2s[co + 11], a = abs_[co];
#pragma unroll
    for (int ci = 0; ci < 16; ++ci) {
      p += w2s[(co * 16 + ci) * 3 + 0] * xr[ci] + w2s[(co * 16 + ci) * 3 + 1] * xr[16 + ci] +
           w2s[(co * 16 + ci) * 3 + 2] * xr[32 + ci];
      q += w2s[((co + 11) * 16 + ci) * 3 + 0] * xr[ci] + w2s[((co + 11) * 16 + ci) * 3 + 1] * xr[16 + ci] +
           w2s[((co + 11) * 16 + ci) * 3 + 2] * xr[32 + ci];
      a += aws[co * 16 + ci] * xr[32 + ci];
    }
    o[co] = (p + a) * sigmoidf_(q);
  }
}

// ---------------- final: out[b,n,:] = z[b,n,:44] @ W[44,128] + bias ----------------
__global__ __launch_bounds__(128) void final_kernel(const float* __restrict__ X3,
                                                    const float* __restrict__ W,
                                                    const float* __restrict__ bias,
                                                    float* __restrict__ out, int rows) {
  __shared__ float Wl[44 * 128];
  __shared__ float zs[44];
  int tid = threadIdx.x;
  for (int i = tid; i < 44 * 128; i += 128) Wl[i] = W[i];
  float bh = bias[tid];
  for (int r = blockIdx.x; r < rows; r += gridDim.x) {
    __syncthreads();
    if (tid < 44) {
      int c = tid >> 1, t = tid & 1;
      int b = r / NN, n = r - b * NN;
      zs[tid] = X3[((long)n * 32 + b * 2 + t) * 22 + c];
    }
    __syncthreads();
    float acc = bh;
#pragma unroll
    for (int k = 0; k < 44; ++k) acc += zs[k] * Wl[k * 128 + tid];
    out[(long)r * 128 + tid] = acc;
  }
}

// CSR slot layout (ints): rowptr[30016] | csr_src[120000] | csr_norm[120000]
#define CSR_STRIDE 270016
#define CSR_RP(base, l)   ((base) + (size_t)(l) * CSR_STRIDE)
#define CSR_SRC(base, l)  ((base) + (size_t)(l) * CSR_STRIDE + 30016)
#define CSR_NRM(base, l)  ((float*)((base) + (size_t)(l) * CSR_STRIDE + 150016))

// ---------------- host-side ChebConv driver (pull-based) ----------------
template <int C, int S, int OSTR, int CHF4, bool FIRST>
static void run_cheb(const int* csrBase, int l0, const float* W, const float* bias,
                     const float* Xn, float* T1, float* T2, float* out, int choff,
                     hipStream_t stream) {
  constexpr int PB = (NN * CHF4 + 255) / 256;
  constexpr int AB = (NN * S + 255) / 256;
  for (int e = 0; e < 2; ++e) {
    const int* rp = CSR_RP(csrBase, l0 + e);
    const int* cs = CSR_SRC(csrBase, l0 + e);
    const float* cn = CSR_NRM(csrBase, l0 + e);
    pull_kernel<CHF4><<<PB, 256, 0, stream>>>(rp, cs, cn, Xn, T1, -1.f);
    pull_kernel<CHF4><<<PB, 256, 0, stream>>>(rp, cs, cn, T1, T2, -2.f);
    if (FIRST && e == 0)
      accum_kernel<C, S, OSTR, false><<<AB, 256, 0, stream>>>(Xn, T1, T2, W, bias, out, choff);
    else
      accum_kernel<C, S, OSTR, true><<<AB, 256, 0, stream>>>(Xn, T1, T2, W + (size_t)e * 3 * C * C,
                                                             bias + (size_t)e * C, out, choff);
  }
}

extern "C" void kernel_launch(void* const* d_in, const int* in_sizes, int n_in,
                              void* d_out, int out_size, void* d_ws, size_t ws_size,
                              hipStream_t stream) {
  const float* x    = (const float*)d_in[0];
  const int*   hg   = (const int*)d_in[1];
  const int*   tg   = (const int*)d_in[2];
  const float* t1w  = (const float*)d_in[3];
  const float* t1b  = (const float*)d_in[4];
  const float* h1W  = (const float*)d_in[5];
  const float* h1b  = (const float*)d_in[6];
  const float* g1W  = (const float*)d_in[7];
  const float* g1b  = (const float*)d_in[8];
  const float* a2w  = (const float*)d_in[9];
  const float* a2b  = (const float*)d_in[10];
  const float* t2w  = (const float*)d_in[11];
  const float* t2b  = (const float*)d_in[12];
  const float* h2W  = (const float*)d_in[13];
  const float* h2b  = (const float*)d_in[14];
  const float* g2W  = (const float*)d_in[15];
  const float* g2b  = (const float*)d_in[16];
  const float* outw = (const float*)d_in[17];
  const float* outb = (const float*)d_in[18];
  float* out = (float*)d_out;

  // workspace layout (floats)
  float* ws = (float*)d_ws;
  float* A  = ws;                        // 15,360,000  X1 [N][64][8]  -> later X2n [N][32][11]
  float* Bf = A + 15360000;              // 15,360,000  T1
  float* Cf = Bf + 15360000;             // 15,360,000  T2
  float* D  = Cf + 15360000;             // 30,720,000  X2in [N][64][16] -> later X3 [N][32][22]
  int* csrBase = (int*)(D + 30720000);   // 4 * CSR_STRIDE ints
  int* tmp     = csrBase + 4 * CSR_STRIDE; // deg_out | deg_in | cursor (3 * 30000)
  int* deg_out = tmp;
  int* deg_in  = tmp + NN;
  int* cursor  = tmp + 2 * NN;

  // --- build CSR (sorted by dst) + norms for all 4 edge lists ---
  const int* glist[2] = {hg, tg};
  for (int g = 0; g < 2; ++g)
    for (int e = 0; e < 2; ++e) {
      int l = g * 2 + e;
      const int* src = glist[g] + (size_t)(2 * e) * EDGES;
      const int* dst = src + EDGES;
      hipMemsetAsync(deg_out, 0, 2 * NN * sizeof(int), stream);
      count_kernel<<<(EDGES + 255) / 256, 256, 0, stream>>>(src, dst, deg_out, deg_in);
      scan_kernel<<<1, 1024, 0, stream>>>(deg_in, CSR_RP(csrBase, l));
      cursor_init_kernel<<<(NN + 255) / 256, 256, 0, stream>>>(CSR_RP(csrBase, l), cursor);
      fill_kernel<<<(EDGES + 255) / 256, 256, 0, stream>>>(src, dst, deg_out, deg_in, cursor,
                                                           CSR_SRC(csrBase, l), CSR_NRM(csrBase, l));
    }

  // --- block1 temporal GLU ---
  glu1_kernel<<<NN * 64 / 256, 256, 0, stream>>>(x, t1w, t1b, A);

  // --- block1 hetcheb (hg -> ch 0..7, tg -> ch 8..15 of X2in=D) ---
  run_cheb<8, 64, 16, 128, true >(csrBase, 0, h1W, h1b, A, Bf, Cf, D, 0, stream);
  run_cheb<8, 64, 16, 128, true >(csrBase, 2, g1W, g1b, A, Bf, Cf, D, 8, stream);

  // --- block2 align + temporal GLU: D (X2in) -> A (X2n) ---
  glu2_kernel<<<NN * 32 / 256, 256, 0, stream>>>(D, t2w, t2b, a2w, a2b, A);

  // --- block2 hetcheb (hg -> ch 0..10, tg -> ch 11..21 of X3=D) ---
  run_cheb<11, 32, 22, 88, true >(csrBase, 0, h2W, h2b, A, Bf, Cf, D, 0, stream);
  run_cheb<11, 32, 22, 88, true >(csrBase, 2, g2W, g2b, A, Bf, Cf, D, 11, stream);

  // --- final linear ---
  final_kernel<<<2048, 128, 0, stream>>>(D, outw, outb, out, 16 * NN);
}

// Round 3
// 1151.515 us; speedup vs baseline: 10.4833x; 1.7061x over previous
//
#include <hip/hip_runtime.h>
#include <math.h>

#define EDGES 120000
#define NN    30000
#define NCH   118   // ceil(30000/256)

__device__ __forceinline__ float sigmoidf_(float x) { return 1.f / (1.f + __expf(-x)); }

// CSR slot layout (ints): rowptr[30016] | csr_src[120000] | csr_norm[120000]
#define CSR_STRIDE 270016
#define CSR_RP(base, l)   ((base) + (size_t)(l) * CSR_STRIDE)
#define CSR_SRC(base, l)  ((base) + (size_t)(l) * CSR_STRIDE + 30016)
#define CSR_NRM(base, l)  ((float*)((base) + (size_t)(l) * CSR_STRIDE + 150016))

// ---------------- CSR build: count degrees for all 4 edge lists ----------------
__global__ void count_all_kernel(const int* __restrict__ hg, const int* __restrict__ tg,
                                 int* __restrict__ degO, int* __restrict__ degI) {
  int tid = blockIdx.x * blockDim.x + threadIdx.x;
  if (tid >= 4 * EDGES) return;
  int l = tid / EDGES, j = tid - l * EDGES;
  const int* G = (l < 2) ? hg : tg;
  const int* src = G + (size_t)(l & 1) * 2 * EDGES;
  const int* dst = src + EDGES;
  atomicAdd(&degO[l * NN + src[j]], 1);
  atomicAdd(&degI[l * NN + dst[j]], 1);
}

// ---------------- chunked scan phase 1: local inclusive scan per 256-chunk ----------------
__global__ __launch_bounds__(256) void scan1_kernel(const int* __restrict__ degI,
                                                    int* __restrict__ csrBase,
                                                    int* __restrict__ partials) {
  int l = blockIdx.x / NCH, ch = blockIdx.x - l * NCH;
  int tid = threadIdx.x;
  int i = ch * 256 + tid;
  __shared__ int buf[256];
  int v = (i < NN) ? degI[l * NN + i] : 0;
  buf[tid] = v;
  __syncthreads();
  for (int off = 1; off < 256; off <<= 1) {
    int t = (tid >= off) ? buf[tid - off] : 0;
    __syncthreads();
    buf[tid] += t;
    __syncthreads();
  }
  int* rp = CSR_RP(csrBase, l);
  if (i < NN) rp[i + 1] = buf[tid];
  if (tid == 255) partials[l * NCH + ch] = buf[255];
}

// ---------------- scan phase 2: exclusive-scan the 118 partials per list ----------------
__global__ __launch_bounds__(128) void scan2_kernel(int* __restrict__ partials) {
  __shared__ int buf[128];
  int tid = threadIdx.x;
  for (int l = 0; l < 4; ++l) {
    int v = (tid < NCH) ? partials[l * NCH + tid] : 0;
    buf[tid] = v;
    __syncthreads();
    for (int off = 1; off < 128; off <<= 1) {
      int t = (tid >= off) ? buf[tid - off] : 0;
      __syncthreads();
      buf[tid] += t;
      __syncthreads();
    }
    if (tid < NCH) partials[l * NCH + tid] = buf[tid] - v;  // exclusive
    __syncthreads();
  }
}

// ---------------- scan phase 3: add chunk offsets, init cursor ----------------
__global__ __launch_bounds__(256) void fixup_kernel(int* __restrict__ csrBase,
                                                    int* __restrict__ cursor,
                                                    const int* __restrict__ partials) {
  int l = blockIdx.x / NCH, ch = blockIdx.x - l * NCH;
  int i = ch * 256 + threadIdx.x;
  int* rp = CSR_RP(csrBase, l);
  int off = partials[l * NCH + ch];
  if (i < NN) {
    int val = rp[i + 1] + off;
    rp[i + 1] = val;
    if (i + 1 < NN) cursor[l * NN + i + 1] = val;
  }
  if (i == 0) { rp[0] = 0; cursor[l * NN] = 0; }
}

// ---------------- CSR fill (all 4 lists, computes edge norm) ----------------
__global__ void fill_all_kernel(const int* __restrict__ hg, const int* __restrict__ tg,
                                const int* __restrict__ degO, const int* __restrict__ degI,
                                int* __restrict__ cursor, int* __restrict__ csrBase) {
  int tid = blockIdx.x * blockDim.x + threadIdx.x;
  if (tid >= 4 * EDGES) return;
  int l = tid / EDGES, j = tid - l * EDGES;
  const int* G = (l < 2) ? hg : tg;
  const int* src = G + (size_t)(l & 1) * 2 * EDGES;
  const int* dst = src + EDGES;
  int s = src[j], d = dst[j];
  int doo = degO[l * NN + s]; if (doo < 1) doo = 1;
  int dii = degI[l * NN + d]; if (dii < 1) dii = 1;
  float nm = rsqrtf((float)doo) * rsqrtf((float)dii);
  int p = atomicAdd(&cursor[l * NN + d], 1);
  CSR_SRC(csrBase, l)[p] = s;
  CSR_NRM(csrBase, l)[p] = nm;
}

// ---------------- block1 temporal GLU conv: x[B,N,6,1] -> X1[N][64][8] ----------------
__global__ void glu1_kernel(const float* __restrict__ x, const float* __restrict__ w,
                            const float* __restrict__ b, float* __restrict__ X1) {
  int idx = blockIdx.x * blockDim.x + threadIdx.x;   // idx = n*64 + s, s = b*4 + t
  if (idx >= NN * 64) return;
  int n = idx >> 6, s = idx & 63;
  int bb = s >> 2, t = s & 3;
  const float* xb = x + ((long)bb * NN + n) * 6;
  float x0 = xb[t], x1 = xb[t + 1], x2 = xb[t + 2];
  float* o = X1 + (long)idx * 8;
#pragma unroll
  for (int c = 0; c < 8; ++c) {
    float p = w[c * 3 + 0] * x0 + w[c * 3 + 1] * x1 + w[c * 3 + 2] * x2 + b[c];
    float q = w[(c + 8) * 3 + 0] * x0 + w[(c + 8) * 3 + 1] * x1 + w[(c + 8) * 3 + 2] * x2 + b[c + 8];
    float al = (c == 0) ? x2 : 0.f;
    o[c] = (p + al) * sigmoidf_(q);
  }
}

// ---------------- CSR pull: out[n] = -sum_e norm[e] * in[csrc[e]]  (rows of ROWF4 float4) ----------------
template <int ROWF4>
__global__ __launch_bounds__(256) void pull_kernel(const int* __restrict__ rowptr,
                                                   const int* __restrict__ csrc,
                                                   const float* __restrict__ cnorm,
                                                   const float* __restrict__ in,
                                                   float* __restrict__ out) {
  int tid = blockIdx.x * 256 + threadIdx.x;
  int n = tid / ROWF4, j = tid - n * ROWF4;
  const float4* in4 = reinterpret_cast<const float4*>(in);
  float ax = 0.f, ay = 0.f, az = 0.f, aw = 0.f;
  int beg = rowptr[n], end = rowptr[n + 1];
  for (int e = beg; e < end; ++e) {
    float nm = cnorm[e];
    float4 v = in4[(long)csrc[e] * ROWF4 + j];
    ax += nm * v.x; ay += nm * v.y; az += nm * v.z; aw += nm * v.w;
  }
  float4 o; o.x = -ax; o.y = -ay; o.z = -az; o.w = -aw;
  reinterpret_cast<float4*>(out)[tid] = o;
}

// ---------------- fused pull2 + Chebyshev combine ----------------
// out[n][s][0..C) (=|+=) X*(W0-W2) + T1own*W1 + (-2*gather(T1))*W2 + bias
template <int C, int CP, int S, bool ADD>
__global__ __launch_bounds__(256) void cheb_fused_kernel(
    const int* __restrict__ rowptr, const int* __restrict__ csrc, const float* __restrict__ cnorm,
    const float* __restrict__ X, const float* __restrict__ T1,
    const float* __restrict__ W, const float* __restrict__ bias, float* __restrict__ out) {
  constexpr int ROW = S * CP;
  __shared__ float w0[C * C], w1[C * C], w2[C * C], bb[C];
  for (int i = threadIdx.x; i < C * C; i += 256) {
    w0[i] = W[i] - W[2 * C * C + i];
    w1[i] = W[C * C + i];
    w2[i] = -2.f * W[2 * C * C + i];   // fold the 2*prop scale
  }
  if (threadIdx.x < C) bb[threadIdx.x] = bias[threadIdx.x];
  __syncthreads();
  int tid = blockIdx.x * 256 + threadIdx.x;     // tid = n*S + s (grid exact)
  int n = tid / S, s = tid - n * S;
  int beg = rowptr[n], end = rowptr[n + 1];
  float acc[CP];
#pragma unroll
  for (int c = 0; c < CP; ++c) acc[c] = 0.f;
  const float4* T14 = reinterpret_cast<const float4*>(T1);
  for (int e = beg; e < end; ++e) {
    float nm = cnorm[e];
    long b4 = ((long)csrc[e] * ROW + s * CP) >> 2;
#pragma unroll
    for (int q = 0; q < CP / 4; ++q) {
      float4 v = T14[b4 + q];
      acc[4 * q + 0] += nm * v.x; acc[4 * q + 1] += nm * v.y;
      acc[4 * q + 2] += nm * v.z; acc[4 * q + 3] += nm * v.w;
    }
  }
  long base4 = ((long)tid * CP) >> 2;
  float x0[CP], t1o[CP];
  const float4* X4 = reinterpret_cast<const float4*>(X);
#pragma unroll
  for (int q = 0; q < CP / 4; ++q) {
    float4 xv = X4[base4 + q]; float4 tv = T14[base4 + q];
    x0[4 * q] = xv.x; x0[4 * q + 1] = xv.y; x0[4 * q + 2] = xv.z; x0[4 * q + 3] = xv.w;
    t1o[4 * q] = tv.x; t1o[4 * q + 1] = tv.y; t1o[4 * q + 2] = tv.z; t1o[4 * q + 3] = tv.w;
  }
  float z[CP];
#pragma unroll
  for (int d = 0; d < C; ++d) {
    float zz = bb[d];
#pragma unroll
    for (int c = 0; c < C; ++c)
      zz += x0[c] * w0[c * C + d] + t1o[c] * w1[c * C + d] + acc[c] * w2[c * C + d];
    z[d] = zz;
  }
#pragma unroll
  for (int d = C; d < CP; ++d) z[d] = 0.f;
  float4* o4 = reinterpret_cast<float4*>(out) + base4;
#pragma unroll
  for (int q = 0; q < CP / 4; ++q) {
    float4 zv = make_float4(z[4 * q], z[4 * q + 1], z[4 * q + 2], z[4 * q + 3]);
    if (ADD) { float4 ov = o4[q]; zv.x += ov.x; zv.y += ov.y; zv.z += ov.z; zv.w += ov.w; }
    o4[q] = zv;
  }
}

// ---------------- block2 align(1x1) + temporal GLU: H/T [N][64][8] -> X2n [N][32][12] padded ----------------
__global__ __launch_bounds__(256) void glu2_kernel(const float* __restrict__ H, const float* __restrict__ Tt,
                                                   const float* __restrict__ w2, const float* __restrict__ b2,
                                                   const float* __restrict__ aw, const float* __restrict__ ab,
                                                   float* __restrict__ X2n) {
  __shared__ float w2s[22 * 16 * 3], b2s[22], aws[11 * 16], abs_[11];
  for (int i = threadIdx.x; i < 22 * 16 * 3; i += 256) w2s[i] = w2[i];
  if (threadIdx.x < 22) b2s[threadIdx.x] = b2[threadIdx.x];
  for (int i = threadIdx.x; i < 11 * 16; i += 256) aws[i] = aw[i];
  if (threadIdx.x < 11) abs_[threadIdx.x] = ab[threadIdx.x];
  __syncthreads();
  int idx = blockIdx.x * 256 + threadIdx.x;   // idx = n*32 + s2, s2 = b*2 + t
  int n = idx >> 5, s = idx & 31;
  int bb = s >> 1, t = s & 1;
  long rbase = ((long)n * 64 + bb * 4 + t) * 8;   // 24 consecutive floats = 3 time taps
  float hv[24], tv[24];
  const float4* H4 = reinterpret_cast<const float4*>(H + rbase);
  const float4* T4 = reinterpret_cast<const float4*>(Tt + rbase);
#pragma unroll
  for (int q = 0; q < 6; ++q) {
    float4 a = H4[q]; hv[4 * q] = a.x; hv[4 * q + 1] = a.y; hv[4 * q + 2] = a.z; hv[4 * q + 3] = a.w;
    float4 b_ = T4[q]; tv[4 * q] = b_.x; tv[4 * q + 1] = b_.y; tv[4 * q + 2] = b_.z; tv[4 * q + 3] = b_.w;
  }
  float* o = X2n + (long)idx * 12;
#pragma unroll
  for (int co = 0; co < 11; ++co) {
    float p = b2s[co], q = b2s[co + 11], a = abs_[co];
#pragma unroll
    for (int ci = 0; ci < 16; ++ci) {
      float v0 = (ci < 8) ? hv[ci] : tv[ci - 8];
      float v1 = (ci < 8) ? hv[8 + ci] : tv[ci];
      float v2 = (ci < 8) ? hv[16 + ci] : tv[8 + ci];
      p += w2s[(co * 16 + ci) * 3 + 0] * v0 + w2s[(co * 16 + ci) * 3 + 1] * v1 +
           w2s[(co * 16 + ci) * 3 + 2] * v2;
      q += w2s[((co + 11) * 16 + ci) * 3 + 0] * v0 + w2s[((co + 11) * 16 + ci) * 3 + 1] * v1 +
           w2s[((co + 11) * 16 + ci) * 3 + 2] * v2;
      a += aws[co * 16 + ci] * v2;
    }
    o[co] = (p + a) * sigmoidf_(q);
  }
  o[11] = 0.f;
}

// ---------------- final: out[r,:] = z[r,:44] @ W[44,128] + bias, z from H2/T2 padded buffers ----------------
__global__ __launch_bounds__(256) void final_kernel(const float* __restrict__ H2, const float* __restrict__ T2b,
                                                    const float* __restrict__ W, const float* __restrict__ bias,
                                                    float* __restrict__ out) {
  __shared__ float zsr[64][48];
  int tid = threadIdx.x;
  long r0 = (long)blockIdx.x * 64;
  // stage 64 rows: per row 6 float4 from H2 + 6 from T2b
#pragma unroll
  for (int it = 0; it < 3; ++it) {
    int item = it * 256 + tid;          // 768 items
    int row = item / 12, piece = item - row * 12;
    long r = r0 + row;
    int b = (int)(r / NN), n = (int)(r - (long)b * NN);
    const float4* srcb = reinterpret_cast<const float4*>(piece < 6 ? H2 : T2b);
    int f4i = (piece < 6) ? piece : piece - 6;
    float4 v = srcb[((long)n * 32 + b * 2) * 3 + f4i];
    *reinterpret_cast<float4*>(&zsr[row][(piece < 6 ? 0 : 24) + f4i * 4]) = v;
  }
  int c = tid & 127, h = tid >> 7;
  float wreg[44];
#pragma unroll
  for (int k = 0; k < 44; ++k) wreg[k] = W[k * 128 + c];
  float bh = bias[c];
  __syncthreads();
  for (int row = h * 32; row < h * 32 + 32; ++row) {
    float acc = bh;
#pragma unroll
    for (int k = 0; k < 44; ++k) {
      int c_ = k >> 1, t = k & 1;
      int off = (c_ < 11) ? (t * 12 + c_) : (24 + t * 12 + (c_ - 11));
      acc += zsr[row][off] * wreg[k];
    }
    out[(r0 + row) * 128 + c] = acc;
  }
}

// ---------------- host-side ChebConv driver (pull + fused) ----------------
template <int C, int CP, int S>
static void run_graph(const int* csrBase, int l0, const float* W, const float* bias,
                      const float* Xn, float* T1, float* out, hipStream_t stream) {
  constexpr int ROWF4 = S * CP / 4;
  for (int e = 0; e < 2; ++e) {
    const int* rp = CSR_RP(csrBase, l0 + e);
    const int* cs = CSR_SRC(csrBase, l0 + e);
    const float* cn = CSR_NRM(csrBase, l0 + e);
    pull_kernel<ROWF4><<<NN * ROWF4 / 256, 256, 0, stream>>>(rp, cs, cn, Xn, T1);
    if (e == 0)
      cheb_fused_kernel<C, CP, S, false><<<NN * S / 256, 256, 0, stream>>>(rp, cs, cn, Xn, T1, W, bias, out);
    else
      cheb_fused_kernel<C, CP, S, true><<<NN * S / 256, 256, 0, stream>>>(rp, cs, cn, Xn, T1,
                                                                          W + 3 * C * C, bias + C, out);
  }
}

extern "C" void kernel_launch(void* const* d_in, const int* in_sizes, int n_in,
                              void* d_out, int out_size, void* d_ws, size_t ws_size,
                              hipStream_t stream) {
  const float* x    = (const float*)d_in[0];
  const int*   hg   = (const int*)d_in[1];
  const int*   tg   = (const int*)d_in[2];
  const float* t1w  = (const float*)d_in[3];
  const float* t1b  = (const float*)d_in[4];
  const float* h1W  = (const float*)d_in[5];
  const float* h1b  = (const float*)d_in[6];
  const float* g1W  = (const float*)d_in[7];
  const float* g1b  = (const float*)d_in[8];
  const float* a2w  = (const float*)d_in[9];
  const float* a2b  = (const float*)d_in[10];
  const float* t2w  = (const float*)d_in[11];
  const float* t2b  = (const float*)d_in[12];
  const float* h2W  = (const float*)d_in[13];
  const float* h2b  = (const float*)d_in[14];
  const float* g2W  = (const float*)d_in[15];
  const float* g2b  = (const float*)d_in[16];
  const float* outw = (const float*)d_in[17];
  const float* outb = (const float*)d_in[18];
  float* out = (float*)d_out;

  // workspace layout (floats)
  float* ws = (float*)d_ws;
  float* A  = ws;                 // X1 [N][64][8] -> later X2n [N][32][12]
  float* Bf = A + 15360000;       // T1
  float* Cf = Bf + 15360000;      // outH1 [N][64][8] -> later outH2 [N][32][12]
  float* Df = Cf + 15360000;      // outT1 [N][64][8] -> later outT2 [N][32][12]
  int* csrBase  = (int*)(Df + 15360000);     // 4 * CSR_STRIDE ints
  int* degO     = csrBase + 4 * CSR_STRIDE;  // 4*NN
  int* degI     = degO + 4 * NN;             // 4*NN
  int* cursor   = degI + 4 * NN;             // 4*NN
  int* partials = cursor + 4 * NN;           // 4*NCH

  // --- build CSR (sorted by dst) + norms for all 4 edge lists, batched ---
  hipMemsetAsync(degO, 0, 8 * NN * sizeof(int), stream);
  count_all_kernel<<<(4 * EDGES + 255) / 256, 256, 0, stream>>>(hg, tg, degO, degI);
  scan1_kernel<<<4 * NCH, 256, 0, stream>>>(degI, csrBase, partials);
  scan2_kernel<<<1, 128, 0, stream>>>(partials);
  fixup_kernel<<<4 * NCH, 256, 0, stream>>>(csrBase, cursor, partials);
  fill_all_kernel<<<(4 * EDGES + 255) / 256, 256, 0, stream>>>(hg, tg, degO, degI, cursor, csrBase);

  // --- block1 temporal GLU ---
  glu1_kernel<<<NN * 64 / 256, 256, 0, stream>>>(x, t1w, t1b, A);

  // --- block1 hetcheb: hg -> Cf, tg -> Df ---
  run_graph<8, 8, 64>(csrBase, 0, h1W, h1b, A, Bf, Cf, stream);
  run_graph<8, 8, 64>(csrBase, 2, g1W, g1b, A, Bf, Df, stream);

  // --- block2 align + temporal GLU: (Cf, Df) -> A (padded X2n) ---
  glu2_kernel<<<NN * 32 / 256, 256, 0, stream>>>(Cf, Df, t2w, t2b, a2w, a2b, A);

  // --- block2 hetcheb: hg -> Cf, tg -> Df (padded [N][32][12]) ---
  run_graph<11, 12, 32>(csrBase, 0, h2W, h2b, A, Bf, Cf, stream);
  run_graph<11, 12, 32>(csrBase, 2, g2W, g2b, A, Bf, Df, stream);

  // --- final linear ---
  final_kernel<<<7500, 256, 0, stream>>>(Cf, Df, outw, outb, out);
}

// Round 4
// 1016.880 us; speedup vs baseline: 11.8713x; 1.1324x over previous
//
#include <hip/hip_runtime.h>
#include <math.h>

#define EDGES 120000
#define NN    30000
#define NCH   118   // ceil(30000/256)

__device__ __forceinline__ float sigmoidf_(float x) { return 1.f / (1.f + __expf(-x)); }

// CSR slot layout (ints): rowptr[30016] | csr_src[120000] | csr_norm[120000]
#define CSR_STRIDE 270016
#define CSR_RP(base, l)   ((base) + (size_t)(l) * CSR_STRIDE)
#define CSR_SRC(base, l)  ((base) + (size_t)(l) * CSR_STRIDE + 30016)
#define CSR_NRM(base, l)  ((float*)((base) + (size_t)(l) * CSR_STRIDE + 150016))

// ---------------- CSR build: count degrees for all 4 edge lists ----------------
__global__ void count_all_kernel(const int* __restrict__ hg, const int* __restrict__ tg,
                                 int* __restrict__ degO, int* __restrict__ degI) {
  int tid = blockIdx.x * blockDim.x + threadIdx.x;
  if (tid >= 4 * EDGES) return;
  int l = tid / EDGES, j = tid - l * EDGES;
  const int* G = (l < 2) ? hg : tg;
  const int* src = G + (size_t)(l & 1) * 2 * EDGES;
  const int* dst = src + EDGES;
  atomicAdd(&degO[l * NN + src[j]], 1);
  atomicAdd(&degI[l * NN + dst[j]], 1);
}

// ---------------- chunked scan phase 1 ----------------
__global__ __launch_bounds__(256) void scan1_kernel(const int* __restrict__ degI,
                                                    int* __restrict__ csrBase,
                                                    int* __restrict__ partials) {
  int l = blockIdx.x / NCH, ch = blockIdx.x - l * NCH;
  int tid = threadIdx.x;
  int i = ch * 256 + tid;
  __shared__ int buf[256];
  int v = (i < NN) ? degI[l * NN + i] : 0;
  buf[tid] = v;
  __syncthreads();
  for (int off = 1; off < 256; off <<= 1) {
    int t = (tid >= off) ? buf[tid - off] : 0;
    __syncthreads();
    buf[tid] += t;
    __syncthreads();
  }
  int* rp = CSR_RP(csrBase, l);
  if (i < NN) rp[i + 1] = buf[tid];
  if (tid == 255) partials[l * NCH + ch] = buf[255];
}

// ---------------- scan phase 2 ----------------
__global__ __launch_bounds__(128) void scan2_kernel(int* __restrict__ partials) {
  __shared__ int buf[128];
  int tid = threadIdx.x;
  for (int l = 0; l < 4; ++l) {
    int v = (tid < NCH) ? partials[l * NCH + tid] : 0;
    buf[tid] = v;
    __syncthreads();
    for (int off = 1; off < 128; off <<= 1) {
      int t = (tid >= off) ? buf[tid - off] : 0;
      __syncthreads();
      buf[tid] += t;
      __syncthreads();
    }
    if (tid < NCH) partials[l * NCH + tid] = buf[tid] - v;  // exclusive
    __syncthreads();
  }
}

// ---------------- scan phase 3 ----------------
__global__ __launch_bounds__(256) void fixup_kernel(int* __restrict__ csrBase,
                                                    int* __restrict__ cursor,
                                                    const int* __restrict__ partials) {
  int l = blockIdx.x / NCH, ch = blockIdx.x - l * NCH;
  int i = ch * 256 + threadIdx.x;
  int* rp = CSR_RP(csrBase, l);
  int off = partials[l * NCH + ch];
  if (i < NN) {
    int val = rp[i + 1] + off;
    rp[i + 1] = val;
    if (i + 1 < NN) cursor[l * NN + i + 1] = val;
  }
  if (i == 0) { rp[0] = 0; cursor[l * NN] = 0; }
}

// ---------------- CSR fill ----------------
__global__ void fill_all_kernel(const int* __restrict__ hg, const int* __restrict__ tg,
                                const int* __restrict__ degO, const int* __restrict__ degI,
                                int* __restrict__ cursor, int* __restrict__ csrBase) {
  int tid = blockIdx.x * blockDim.x + threadIdx.x;
  if (tid >= 4 * EDGES) return;
  int l = tid / EDGES, j = tid - l * EDGES;
  const int* G = (l < 2) ? hg : tg;
  const int* src = G + (size_t)(l & 1) * 2 * EDGES;
  const int* dst = src + EDGES;
  int s = src[j], d = dst[j];
  int doo = degO[l * NN + s]; if (doo < 1) doo = 1;
  int dii = degI[l * NN + d]; if (dii < 1) dii = 1;
  float nm = rsqrtf((float)doo) * rsqrtf((float)dii);
  int p = atomicAdd(&cursor[l * NN + d], 1);
  CSR_SRC(csrBase, l)[p] = s;
  CSR_NRM(csrBase, l)[p] = nm;
}

// ---------------- block1 temporal GLU conv: x[B,N,6,1] -> X1[N][64][8] ----------------
__global__ void glu1_kernel(const float* __restrict__ x, const float* __restrict__ w,
                            const float* __restrict__ b, float* __restrict__ X1) {
  int idx = blockIdx.x * blockDim.x + threadIdx.x;
  if (idx >= NN * 64) return;
  int n = idx >> 6, s = idx & 63;
  int bb = s >> 2, t = s & 3;
  const float* xb = x + ((long)bb * NN + n) * 6;
  float x0 = xb[t], x1 = xb[t + 1], x2 = xb[t + 2];
  float* o = X1 + (long)idx * 8;
#pragma unroll
  for (int c = 0; c < 8; ++c) {
    float p = w[c * 3 + 0] * x0 + w[c * 3 + 1] * x1 + w[c * 3 + 2] * x2 + b[c];
    float q = w[(c + 8) * 3 + 0] * x0 + w[(c + 8) * 3 + 1] * x1 + w[(c + 8) * 3 + 2] * x2 + b[c + 8];
    float al = (c == 0) ? x2 : 0.f;
    o[c] = (p + al) * sigmoidf_(q);
  }
}

// ---------------- batched CSR pull (both etypes): outE[n] = -sum norm*in[src] ----------------
template <int ROWF4>
__global__ __launch_bounds__(256) void pull_both_kernel(
    const int* __restrict__ rp0, const int* __restrict__ cs0, const float* __restrict__ cn0,
    const int* __restrict__ rp1, const int* __restrict__ cs1, const float* __restrict__ cn1,
    const float* __restrict__ in, float* __restrict__ out0, float* __restrict__ out1) {
  int gtid = blockIdx.x * 256 + threadIdx.x;
  int et = gtid / (NN * ROWF4);
  int tid = gtid - et * (NN * ROWF4);
  int n = tid / ROWF4, j = tid - n * ROWF4;
  const int* rowptr = et ? rp1 : rp0;
  const int* csrc   = et ? cs1 : cs0;
  const float* cnorm = et ? cn1 : cn0;
  float* out = et ? out1 : out0;
  const float4* in4 = reinterpret_cast<const float4*>(in);
  float ax = 0.f, ay = 0.f, az = 0.f, aw = 0.f;
  int beg = rowptr[n], end = rowptr[n + 1];
  for (int e = beg; e < end; ++e) {
    float nm = cnorm[e];
    float4 v = in4[(long)csrc[e] * ROWF4 + j];
    ax += nm * v.x; ay += nm * v.y; az += nm * v.z; aw += nm * v.w;
  }
  float4 o; o.x = -ax; o.y = -ay; o.z = -az; o.w = -aw;
  reinterpret_cast<float4*>(out)[tid] = o;
}

// ---------------- fused Chebyshev combine, BOTH etypes, single write ----------------
// out = X*(W0a-W2a+W0b-W2b) + T1a*W1a + T1b*W1b + gth_a(T1a)*(-2W2a) + gth_b(T1b)*(-2W2b) + ba+bb
template <int C, int CP, int S>
__global__ __launch_bounds__(256) void cheb_both_kernel(
    const int* __restrict__ rp0, const int* __restrict__ cs0, const float* __restrict__ cn0,
    const int* __restrict__ rp1, const int* __restrict__ cs1, const float* __restrict__ cn1,
    const float* __restrict__ X, const float* __restrict__ T1a, const float* __restrict__ T1b,
    const float* __restrict__ W, const float* __restrict__ bias, float* __restrict__ out) {
  constexpr int ROW = S * CP;
  constexpr int CC = C * C;
  __shared__ float wx[CC], w1a[CC], w1b[CC], w2a[CC], w2b[CC], bs[C];
  for (int i = threadIdx.x; i < CC; i += 256) {
    float w0A = W[i], w1A = W[CC + i], w2A = W[2 * CC + i];
    float w0B = W[3 * CC + i], w1B = W[4 * CC + i], w2B = W[5 * CC + i];
    wx[i] = w0A - w2A + w0B - w2B;
    w1a[i] = w1A; w1b[i] = w1B;
    w2a[i] = -2.f * w2A; w2b[i] = -2.f * w2B;
  }
  if (threadIdx.x < C) bs[threadIdx.x] = bias[threadIdx.x] + bias[C + threadIdx.x];
  __syncthreads();
  int tid = blockIdx.x * 256 + threadIdx.x;     // tid = n*S + s (grid exact)
  int n = tid / S, s = tid - n * S;
  const float4* A4 = reinterpret_cast<const float4*>(T1a);
  const float4* B4 = reinterpret_cast<const float4*>(T1b);
  float acc0[CP], acc1[CP];
#pragma unroll
  for (int c = 0; c < CP; ++c) { acc0[c] = 0.f; acc1[c] = 0.f; }
  {
    int beg = rp0[n], end = rp0[n + 1];
    for (int e = beg; e < end; ++e) {
      float nm = cn0[e];
      long b4 = ((long)cs0[e] * ROW + s * CP) >> 2;
#pragma unroll
      for (int q = 0; q < CP / 4; ++q) {
        float4 v = A4[b4 + q];
        acc0[4 * q + 0] += nm * v.x; acc0[4 * q + 1] += nm * v.y;
        acc0[4 * q + 2] += nm * v.z; acc0[4 * q + 3] += nm * v.w;
      }
    }
  }
  {
    int beg = rp1[n], end = rp1[n + 1];
    for (int e = beg; e < end; ++e) {
      float nm = cn1[e];
      long b4 = ((long)cs1[e] * ROW + s * CP) >> 2;
#pragma unroll
      for (int q = 0; q < CP / 4; ++q) {
        float4 v = B4[b4 + q];
        acc1[4 * q + 0] += nm * v.x; acc1[4 * q + 1] += nm * v.y;
        acc1[4 * q + 2] += nm * v.z; acc1[4 * q + 3] += nm * v.w;
      }
    }
  }
  long base4 = ((long)tid * CP) >> 2;
  float x0[CP], ta[CP], tb[CP];
  const float4* X4 = reinterpret_cast<const float4*>(X);
#pragma unroll
  for (int q = 0; q < CP / 4; ++q) {
    float4 xv = X4[base4 + q]; float4 av = A4[base4 + q]; float4 bv = B4[base4 + q];
    x0[4 * q] = xv.x; x0[4 * q + 1] = xv.y; x0[4 * q + 2] = xv.z; x0[4 * q + 3] = xv.w;
    ta[4 * q] = av.x; ta[4 * q + 1] = av.y; ta[4 * q + 2] = av.z; ta[4 * q + 3] = av.w;
    tb[4 * q] = bv.x; tb[4 * q + 1] = bv.y; tb[4 * q + 2] = bv.z; tb[4 * q + 3] = bv.w;
  }
  float z[CP];
#pragma unroll
  for (int d = 0; d < C; ++d) {
    float zz = bs[d];
#pragma unroll
    for (int c = 0; c < C; ++c)
      zz += x0[c] * wx[c * C + d] + ta[c] * w1a[c * C + d] + tb[c] * w1b[c * C + d] +
            acc0[c] * w2a[c * C + d] + acc1[c] * w2b[c * C + d];
    z[d] = zz;
  }
#pragma unroll
  for (int d = C; d < CP; ++d) z[d] = 0.f;
  float4* o4 = reinterpret_cast<float4*>(out) + base4;
#pragma unroll
  for (int q = 0; q < CP / 4; ++q)
    o4[q] = make_float4(z[4 * q], z[4 * q + 1], z[4 * q + 2], z[4 * q + 3]);
}

// ---------------- block2 align(1x1) + temporal GLU: H/T [N][64][8] -> X2n [N][32][12] padded ----------------
__global__ __launch_bounds__(256) void glu2_kernel(const float* __restrict__ H, const float* __restrict__ Tt,
                                                   const float* __restrict__ w2, const float* __restrict__ b2,
                                                   const float* __restrict__ aw, const float* __restrict__ ab,
                                                   float* __restrict__ X2n) {
  __shared__ float w2s[22 * 16 * 3], b2s[22], aws[11 * 16], abs_[11];
  for (int i = threadIdx.x; i < 22 * 16 * 3; i += 256) w2s[i] = w2[i];
  if (threadIdx.x < 22) b2s[threadIdx.x] = b2[threadIdx.x];
  for (int i = threadIdx.x; i < 11 * 16; i += 256) aws[i] = aw[i];
  if (threadIdx.x < 11) abs_[threadIdx.x] = ab[threadIdx.x];
  __syncthreads();
  int idx = blockIdx.x * 256 + threadIdx.x;
  int n = idx >> 5, s = idx & 31;
  int bb = s >> 1, t = s & 1;
  long rbase = ((long)n * 64 + bb * 4 + t) * 8;
  float hv[24], tv[24];
  const float4* H4 = reinterpret_cast<const float4*>(H + rbase);
  const float4* T4 = reinterpret_cast<const float4*>(Tt + rbase);
#pragma unroll
  for (int q = 0; q < 6; ++q) {
    float4 a = H4[q]; hv[4 * q] = a.x; hv[4 * q + 1] = a.y; hv[4 * q + 2] = a.z; hv[4 * q + 3] = a.w;
    float4 b_ = T4[q]; tv[4 * q] = b_.x; tv[4 * q + 1] = b_.y; tv[4 * q + 2] = b_.z; tv[4 * q + 3] = b_.w;
  }
  float* o = X2n + (long)idx * 12;
#pragma unroll
  for (int co = 0; co < 11; ++co) {
    float p = b2s[co], q = b2s[co + 11], a = abs_[co];
#pragma unroll
    for (int ci = 0; ci < 16; ++ci) {
      float v0 = (ci < 8) ? hv[ci] : tv[ci - 8];
      float v1 = (ci < 8) ? hv[8 + ci] : tv[ci];
      float v2 = (ci < 8) ? hv[16 + ci] : tv[8 + ci];
      p += w2s[(co * 16 + ci) * 3 + 0] * v0 + w2s[(co * 16 + ci) * 3 + 1] * v1 +
           w2s[(co * 16 + ci) * 3 + 2] * v2;
      q += w2s[((co + 11) * 16 + ci) * 3 + 0] * v0 + w2s[((co + 11) * 16 + ci) * 3 + 1] * v1 +
           w2s[((co + 11) * 16 + ci) * 3 + 2] * v2;
      a += aws[co * 16 + ci] * v2;
    }
    o[co] = (p + a) * sigmoidf_(q);
  }
  o[11] = 0.f;
}

// ---------------- final: out[r,:] = z[r,:44] @ W[44,128] + bias ----------------
// LDS layout zsr[row][48] matches permuted weights wp[48] -> float4 LDS reads.
__global__ __launch_bounds__(256) void final_kernel(const float* __restrict__ H2, const float* __restrict__ T2b,
                                                    const float* __restrict__ W, const float* __restrict__ bias,
                                                    float* __restrict__ out) {
  __shared__ float zsr[64][48];
  int tid = threadIdx.x;
  long r0 = (long)blockIdx.x * 64;
#pragma unroll
  for (int it = 0; it < 3; ++it) {
    int item = it * 256 + tid;          // 768 items = 64 rows x 12 float4
    int row = item / 12, piece = item - row * 12;
    long r = r0 + row;
    int b = (int)(r / NN), n = (int)(r - (long)b * NN);
    const float4* srcb = reinterpret_cast<const float4*>(piece < 6 ? H2 : T2b);
    int f4i = (piece < 6) ? piece : piece - 6;
    float4 v = srcb[((long)n * 32 + b * 2) * 3 + f4i];
    *reinterpret_cast<float4*>(&zsr[row][(piece < 6 ? 0 : 24) + f4i * 4]) = v;
  }
  int c = tid & 127, h = tid >> 7;
  float wp[48];
#pragma unroll
  for (int off = 0; off < 48; ++off) {
    int half = off / 24, r_ = off - half * 24;
    int t = r_ / 12, c_ = r_ - t * 12;
    wp[off] = (c_ == 11) ? 0.f : W[(2 * (c_ + half * 11) + t) * 128 + c];
  }
  float bh = bias[c];
  __syncthreads();
  int rbeg = h * 32;
#pragma unroll 2
  for (int row = rbeg; row < rbeg + 32; ++row) {
    const float4* zr4 = reinterpret_cast<const float4*>(&zsr[row][0]);
    float acc = bh;
#pragma unroll
    for (int q = 0; q < 12; ++q) {
      float4 zv = zr4[q];
      acc = fmaf(zv.x, wp[4 * q + 0], acc);
      acc = fmaf(zv.y, wp[4 * q + 1], acc);
      acc = fmaf(zv.z, wp[4 * q + 2], acc);
      acc = fmaf(zv.w, wp[4 * q + 3], acc);
    }
    out[(r0 + row) * 128 + c] = acc;
  }
}

// ---------------- host-side driver: one graph (2 etypes) ----------------
template <int C, int CP, int S>
static void run_graph(const int* csrBase, int l0, const float* W, const float* bias,
                      const float* Xn, float* T1a, float* T1b, float* out, hipStream_t stream) {
  constexpr int ROWF4 = S * CP / 4;
  const int* rp0 = CSR_RP(csrBase, l0);     const int* cs0 = CSR_SRC(csrBase, l0);
  const float* cn0 = CSR_NRM(csrBase, l0);
  const int* rp1 = CSR_RP(csrBase, l0 + 1); const int* cs1 = CSR_SRC(csrBase, l0 + 1);
  const float* cn1 = CSR_NRM(csrBase, l0 + 1);
  pull_both_kernel<ROWF4><<<2 * NN * ROWF4 / 256, 256, 0, stream>>>(rp0, cs0, cn0, rp1, cs1, cn1,
                                                                    Xn, T1a, T1b);
  cheb_both_kernel<C, CP, S><<<NN * S / 256, 256, 0, stream>>>(rp0, cs0, cn0, rp1, cs1, cn1,
                                                               Xn, T1a, T1b, W, bias, out);
}

extern "C" void kernel_launch(void* const* d_in, const int* in_sizes, int n_in,
                              void* d_out, int out_size, void* d_ws, size_t ws_size,
                              hipStream_t stream) {
  const float* x    = (const float*)d_in[0];
  const int*   hg   = (const int*)d_in[1];
  const int*   tg   = (const int*)d_in[2];
  const float* t1w  = (const float*)d_in[3];
  const float* t1b  = (const float*)d_in[4];
  const float* h1W  = (const float*)d_in[5];
  const float* h1b  = (const float*)d_in[6];
  const float* g1W  = (const float*)d_in[7];
  const float* g1b  = (const float*)d_in[8];
  const float* a2w  = (const float*)d_in[9];
  const float* a2b  = (const float*)d_in[10];
  const float* t2w  = (const float*)d_in[11];
  const float* t2b  = (const float*)d_in[12];
  const float* h2W  = (const float*)d_in[13];
  const float* h2b  = (const float*)d_in[14];
  const float* g2W  = (const float*)d_in[15];
  const float* g2b  = (const float*)d_in[16];
  const float* outw = (const float*)d_in[17];
  const float* outb = (const float*)d_in[18];
  float* out = (float*)d_out;

  // workspace layout (floats)
  float* ws = (float*)d_ws;
  float* A   = ws;                 // X1 [N][64][8] -> later X2n [N][32][12]
  float* T1a = A + 15360000;
  float* T1b = T1a + 15360000;
  float* Cf  = T1b + 15360000;     // outH (also int scratch during CSR build)
  float* Df  = Cf + 15360000;      // outT
  int* csrBase  = (int*)(Df + 15360000);     // 4 * CSR_STRIDE ints
  // CSR-build scratch aliased into Cf (dead until first cheb_both writes Cf)
  int* degO     = (int*)Cf;                  // 4*NN
  int* degI     = degO + 4 * NN;             // 4*NN
  int* cursor   = degI + 4 * NN;             // 4*NN
  int* partials = cursor + 4 * NN;           // 4*NCH

  // --- build CSR (sorted by dst) + norms for all 4 edge lists, batched ---
  hipMemsetAsync(degO, 0, 8 * NN * sizeof(int), stream);
  count_all_kernel<<<(4 * EDGES + 255) / 256, 256, 0, stream>>>(hg, tg, degO, degI);
  scan1_kernel<<<4 * NCH, 256, 0, stream>>>(degI, csrBase, partials);
  scan2_kernel<<<1, 128, 0, stream>>>(partials);
  fixup_kernel<<<4 * NCH, 256, 0, stream>>>(csrBase, cursor, partials);
  fill_all_kernel<<<(4 * EDGES + 255) / 256, 256, 0, stream>>>(hg, tg, degO, degI, cursor, csrBase);

  // --- block1 temporal GLU ---
  glu1_kernel<<<NN * 64 / 256, 256, 0, stream>>>(x, t1w, t1b, A);

  // --- block1 hetcheb: hg -> Cf, tg -> Df ---
  run_graph<8, 8, 64>(csrBase, 0, h1W, h1b, A, T1a, T1b, Cf, stream);
  run_graph<8, 8, 64>(csrBase, 2, g1W, g1b, A, T1a, T1b, Df, stream);

  // --- block2 align + temporal GLU: (Cf, Df) -> A (padded X2n [N][32][12]) ---
  glu2_kernel<<<NN * 32 / 256, 256, 0, stream>>>(Cf, Df, t2w, t2b, a2w, a2b, A);

  // --- block2 hetcheb: hg -> Cf, tg -> Df ---
  run_graph<11, 12, 32>(csrBase, 0, h2W, h2b, A, T1a, T1b, Cf, stream);
  run_graph<11, 12, 32>(csrBase, 2, g2W, g2b, A, T1a, T1b, Df, stream);

  // --- final linear ---
  final_kernel<<<7500, 256, 0, stream>>>(Cf, Df, outw, outb, out);
}

// Round 5
// 891.755 us; speedup vs baseline: 13.5370x; 1.1403x over previous
//
#include <hip/hip_runtime.h>
#include <hip/hip_fp16.h>
#include <math.h>

#define EDGES 120000
#define NN    30000
#define NCH   118   // ceil(30000/256)

__device__ __forceinline__ float sigmoidf_(float x) { return 1.f / (1.f + __expf(-x)); }

union F4H8 { float4 v; __half h[8]; };

__device__ __forceinline__ void unpack8(float4 v, float* f) {
  F4H8 u; u.v = v;
#pragma unroll
  for (int i = 0; i < 8; ++i) f[i] = __half2float(u.h[i]);
}
__device__ __forceinline__ float4 pack8(const float* f) {
  F4H8 u;
#pragma unroll
  for (int i = 0; i < 8; ++i) u.h[i] = __float2half(f[i]);
  return u.v;
}
__device__ __forceinline__ void unpack4(float2 v, float* f) {
  union { float2 v; __half h[4]; } u; u.v = v;
#pragma unroll
  for (int i = 0; i < 4; ++i) f[i] = __half2float(u.h[i]);
}

// CSR slot layout (ints): rowptr[30016] | csr_src[120000] | csr_norm[120000]
#define CSR_STRIDE 270016
#define CSR_RP(base, l)   ((base) + (size_t)(l) * CSR_STRIDE)
#define CSR_SRC(base, l)  ((base) + (size_t)(l) * CSR_STRIDE + 30016)
#define CSR_NRM(base, l)  ((float*)((base) + (size_t)(l) * CSR_STRIDE + 150016))

// ---------------- CSR build ----------------
__global__ void count_all_kernel(const int* __restrict__ hg, const int* __restrict__ tg,
                                 int* __restrict__ degO, int* __restrict__ degI) {
  int tid = blockIdx.x * blockDim.x + threadIdx.x;
  if (tid >= 4 * EDGES) return;
  int l = tid / EDGES, j = tid - l * EDGES;
  const int* G = (l < 2) ? hg : tg;
  const int* src = G + (size_t)(l & 1) * 2 * EDGES;
  const int* dst = src + EDGES;
  atomicAdd(&degO[l * NN + src[j]], 1);
  atomicAdd(&degI[l * NN + dst[j]], 1);
}

__global__ __launch_bounds__(256) void scan1_kernel(const int* __restrict__ degI,
                                                    int* __restrict__ csrBase,
                                                    int* __restrict__ partials) {
  int l = blockIdx.x / NCH, ch = blockIdx.x - l * NCH;
  int tid = threadIdx.x;
  int i = ch * 256 + tid;
  __shared__ int buf[256];
  int v = (i < NN) ? degI[l * NN + i] : 0;
  buf[tid] = v;
  __syncthreads();
  for (int off = 1; off < 256; off <<= 1) {
    int t = (tid >= off) ? buf[tid - off] : 0;
    __syncthreads();
    buf[tid] += t;
    __syncthreads();
  }
  int* rp = CSR_RP(csrBase, l);
  if (i < NN) rp[i + 1] = buf[tid];
  if (tid == 255) partials[l * NCH + ch] = buf[255];
}

__global__ __launch_bounds__(128) void scan2_kernel(int* __restrict__ partials) {
  __shared__ int buf[128];
  int tid = threadIdx.x;
  for (int l = 0; l < 4; ++l) {
    int v = (tid < NCH) ? partials[l * NCH + tid] : 0;
    buf[tid] = v;
    __syncthreads();
    for (int off = 1; off < 128; off <<= 1) {
      int t = (tid >= off) ? buf[tid - off] : 0;
      __syncthreads();
      buf[tid] += t;
      __syncthreads();
    }
    if (tid < NCH) partials[l * NCH + tid] = buf[tid] - v;  // exclusive
    __syncthreads();
  }
}

__global__ __launch_bounds__(256) void fixup_kernel(int* __restrict__ csrBase,
                                                    int* __restrict__ cursor,
                                                    const int* __restrict__ partials) {
  int l = blockIdx.x / NCH, ch = blockIdx.x - l * NCH;
  int i = ch * 256 + threadIdx.x;
  int* rp = CSR_RP(csrBase, l);
  int off = partials[l * NCH + ch];
  if (i < NN) {
    int val = rp[i + 1] + off;
    rp[i + 1] = val;
    if (i + 1 < NN) cursor[l * NN + i + 1] = val;
  }
  if (i == 0) { rp[0] = 0; cursor[l * NN] = 0; }
}

__global__ void fill_all_kernel(const int* __restrict__ hg, const int* __restrict__ tg,
                                const int* __restrict__ degO, const int* __restrict__ degI,
                                int* __restrict__ cursor, int* __restrict__ csrBase) {
  int tid = blockIdx.x * blockDim.x + threadIdx.x;
  if (tid >= 4 * EDGES) return;
  int l = tid / EDGES, j = tid - l * EDGES;
  const int* G = (l < 2) ? hg : tg;
  const int* src = G + (size_t)(l & 1) * 2 * EDGES;
  const int* dst = src + EDGES;
  int s = src[j], d = dst[j];
  int doo = degO[l * NN + s]; if (doo < 1) doo = 1;
  int dii = degI[l * NN + d]; if (dii < 1) dii = 1;
  float nm = rsqrtf((float)doo) * rsqrtf((float)dii);
  int p = atomicAdd(&cursor[l * NN + d], 1);
  CSR_SRC(csrBase, l)[p] = s;
  CSR_NRM(csrBase, l)[p] = nm;
}

// ---------------- block1 temporal GLU conv: x[B,N,6,1] -> X1h [N][64][8] fp16 ----------------
__global__ void glu1_kernel(const float* __restrict__ x, const float* __restrict__ w,
                            const float* __restrict__ b, __half* __restrict__ X1h) {
  int idx = blockIdx.x * blockDim.x + threadIdx.x;   // idx = n*64 + s, s = b*4 + t
  if (idx >= NN * 64) return;
  int n = idx >> 6, s = idx & 63;
  int bb = s >> 2, t = s & 3;
  const float* xb = x + ((long)bb * NN + n) * 6;
  float x0 = xb[t], x1 = xb[t + 1], x2 = xb[t + 2];
  float o[8];
#pragma unroll
  for (int c = 0; c < 8; ++c) {
    float p = w[c * 3 + 0] * x0 + w[c * 3 + 1] * x1 + w[c * 3 + 2] * x2 + b[c];
    float q = w[(c + 8) * 3 + 0] * x0 + w[(c + 8) * 3 + 1] * x1 + w[(c + 8) * 3 + 2] * x2 + b[c + 8];
    float al = (c == 0) ? x2 : 0.f;
    o[c] = (p + al) * sigmoidf_(q);
  }
  reinterpret_cast<float4*>(X1h)[idx] = pack8(o);
}

// ---------------- pull over ALL 4 lists: T1h[l][n] = -sum norm * Xh[src]  (1KB fp16 rows) ----------------
__global__ __launch_bounds__(256) void pull_all_kernel(const int* __restrict__ csrBase,
                                                       const __half* __restrict__ Xh,
                                                       __half* __restrict__ T1hAll) {
  int gtid = blockIdx.x * 256 + threadIdx.x;
  int l = gtid / (NN * 64);
  int t = gtid - l * (NN * 64);
  int n = t >> 6, j = t & 63;
  const int* rp = CSR_RP(csrBase, l);
  const int* cs = CSR_SRC(csrBase, l);
  const float* cn = CSR_NRM(csrBase, l);
  const float4* in4 = reinterpret_cast<const float4*>(Xh);
  float acc[8];
#pragma unroll
  for (int i = 0; i < 8; ++i) acc[i] = 0.f;
  int beg = rp[n], end = rp[n + 1];
  for (int e = beg; e < end; ++e) {
    float nm = cn[e];
    float f[8];
    unpack8(in4[(long)cs[e] * 64 + j], f);
#pragma unroll
    for (int i = 0; i < 8; ++i) acc[i] -= nm * f[i];
  }
  reinterpret_cast<float4*>(T1hAll)[gtid] = pack8(acc);
}

// ---------------- block1 fused Cheb combine, both graphs, fp16 in/out ----------------
__global__ __launch_bounds__(256) void cheb1_kernel(const int* __restrict__ csrBase,
    const __half* __restrict__ Xh, const __half* __restrict__ T1hAll,
    const float* __restrict__ Whg, const float* __restrict__ bhg,
    const float* __restrict__ Wtg, const float* __restrict__ btg,
    __half* __restrict__ outH, __half* __restrict__ outT) {
  constexpr int C = 8, CC = 64;
  __shared__ float wx[CC], w1a[CC], w1b[CC], w2a[CC], w2b[CC], bs[C];
  int gtid = blockIdx.x * 256 + threadIdx.x;
  int g = gtid / (NN * 64);
  int tid = gtid - g * (NN * 64);
  const float* W = g ? Wtg : Whg;
  const float* bias = g ? btg : bhg;
  for (int i = threadIdx.x; i < CC; i += 256) {
    float w0A = W[i], w1A = W[CC + i], w2A = W[2 * CC + i];
    float w0B = W[3 * CC + i], w1B = W[4 * CC + i], w2B = W[5 * CC + i];
    wx[i] = w0A - w2A + w0B - w2B;
    w1a[i] = w1A; w1b[i] = w1B;
    w2a[i] = -2.f * w2A; w2b[i] = -2.f * w2B;
  }
  if (threadIdx.x < C) bs[threadIdx.x] = bias[threadIdx.x] + bias[C + threadIdx.x];
  __syncthreads();
  int n = tid >> 6, s = tid & 63;
  int l0 = 2 * g, l1 = 2 * g + 1;
  const int* rp0 = CSR_RP(csrBase, l0); const int* cs0 = CSR_SRC(csrBase, l0);
  const float* cn0 = CSR_NRM(csrBase, l0);
  const int* rp1 = CSR_RP(csrBase, l1); const int* cs1 = CSR_SRC(csrBase, l1);
  const float* cn1 = CSR_NRM(csrBase, l1);
  const float4* A4 = reinterpret_cast<const float4*>(T1hAll + (size_t)l0 * (NN * 512));
  const float4* B4 = reinterpret_cast<const float4*>(T1hAll + (size_t)l1 * (NN * 512));
  float acc0[C], acc1[C];
#pragma unroll
  for (int c = 0; c < C; ++c) { acc0[c] = 0.f; acc1[c] = 0.f; }
  for (int e = rp0[n], end = rp0[n + 1]; e < end; ++e) {
    float nm = cn0[e];
    float f[8];
    unpack8(A4[(long)cs0[e] * 64 + s], f);
#pragma unroll
    for (int c = 0; c < C; ++c) acc0[c] += nm * f[c];
  }
  for (int e = rp1[n], end = rp1[n + 1]; e < end; ++e) {
    float nm = cn1[e];
    float f[8];
    unpack8(B4[(long)cs1[e] * 64 + s], f);
#pragma unroll
    for (int c = 0; c < C; ++c) acc1[c] += nm * f[c];
  }
  float x0[C], ta[C], tb[C];
  unpack8(reinterpret_cast<const float4*>(Xh)[tid], x0);
  unpack8(A4[tid], ta);
  unpack8(B4[tid], tb);
  float z[C];
#pragma unroll
  for (int d = 0; d < C; ++d) {
    float zz = bs[d];
#pragma unroll
    for (int c = 0; c < C; ++c)
      zz += x0[c] * wx[c * C + d] + ta[c] * w1a[c * C + d] + tb[c] * w1b[c * C + d] +
            acc0[c] * w2a[c * C + d] + acc1[c] * w2b[c * C + d];
    z[d] = zz;
  }
  reinterpret_cast<float4*>(g ? outT : outH)[tid] = pack8(z);
}

// ---------------- block2 align(1x1)+GLU: Cfh/Dfh [N][64][8] fp16 -> X2nh [N][32][16] fp16 ----------------
__global__ __launch_bounds__(256) void glu2_kernel(const __half* __restrict__ H, const __half* __restrict__ Tt,
                                                   const float* __restrict__ w2, const float* __restrict__ b2,
                                                   const float* __restrict__ aw, const float* __restrict__ ab,
                                                   __half* __restrict__ X2nh) {
  __shared__ float w2s[22 * 16 * 3], b2s[22], aws[11 * 16], abs_[11];
  for (int i = threadIdx.x; i < 22 * 16 * 3; i += 256) w2s[i] = w2[i];
  if (threadIdx.x < 22) b2s[threadIdx.x] = b2[threadIdx.x];
  for (int i = threadIdx.x; i < 11 * 16; i += 256) aws[i] = aw[i];
  if (threadIdx.x < 11) abs_[threadIdx.x] = ab[threadIdx.x];
  __syncthreads();
  int idx = blockIdx.x * 256 + threadIdx.x;   // idx = n*32 + s2, s2 = b*2 + t
  int n = idx >> 5, s = idx & 31;
  int bb = s >> 1, t = s & 1;
  long rbase = (long)n * 64 + bb * 4 + t;     // float4 row index (8 halfs per row)
  const float4* H4 = reinterpret_cast<const float4*>(H) + rbase;
  const float4* T4 = reinterpret_cast<const float4*>(Tt) + rbase;
  float hv[24], tv[24];
  unpack8(H4[0], hv); unpack8(H4[1], hv + 8); unpack8(H4[2], hv + 16);
  unpack8(T4[0], tv); unpack8(T4[1], tv + 8); unpack8(T4[2], tv + 16);
  float o[16];
#pragma unroll
  for (int i = 11; i < 16; ++i) o[i] = 0.f;
#pragma unroll
  for (int co = 0; co < 11; ++co) {
    float p = b2s[co], q = b2s[co + 11], a = abs_[co];
#pragma unroll
    for (int ci = 0; ci < 16; ++ci) {
      float v0 = (ci < 8) ? hv[ci] : tv[ci - 8];
      float v1 = (ci < 8) ? hv[8 + ci] : tv[ci];
      float v2 = (ci < 8) ? hv[16 + ci] : tv[8 + ci];
      p += w2s[(co * 16 + ci) * 3 + 0] * v0 + w2s[(co * 16 + ci) * 3 + 1] * v1 +
           w2s[(co * 16 + ci) * 3 + 2] * v2;
      q += w2s[((co + 11) * 16 + ci) * 3 + 0] * v0 + w2s[((co + 11) * 16 + ci) * 3 + 1] * v1 +
           w2s[((co + 11) * 16 + ci) * 3 + 2] * v2;
      a += aws[co * 16 + ci] * v2;
    }
    o[co] = (p + a) * sigmoidf_(q);
  }
  float4* o4 = reinterpret_cast<float4*>(X2nh) + (long)idx * 2;
  o4[0] = pack8(o);
  o4[1] = pack8(o + 8);
}

// ---------------- block2 fused Cheb combine, both graphs, fp16 in, fp32 [N][32][12] out ----------------
__global__ __launch_bounds__(256) void cheb2_kernel(const int* __restrict__ csrBase,
    const __half* __restrict__ Xh, const __half* __restrict__ T1hAll,
    const float* __restrict__ Whg, const float* __restrict__ bhg,
    const float* __restrict__ Wtg, const float* __restrict__ btg,
    float* __restrict__ outH, float* __restrict__ outT) {
  constexpr int C = 11, CC = 121;
  __shared__ float wx[CC], w1a[CC], w1b[CC], w2a[CC], w2b[CC], bs[C];
  int gtid = blockIdx.x * 256 + threadIdx.x;
  int g = gtid / (NN * 32);
  int tid = gtid - g * (NN * 32);
  const float* W = g ? Wtg : Whg;
  const float* bias = g ? btg : bhg;
  for (int i = threadIdx.x; i < CC; i += 256) {
    float w0A = W[i], w1A = W[CC + i], w2A = W[2 * CC + i];
    float w0B = W[3 * CC + i], w1B = W[4 * CC + i], w2B = W[5 * CC + i];
    wx[i] = w0A - w2A + w0B - w2B;
    w1a[i] = w1A; w1b[i] = w1B;
    w2a[i] = -2.f * w2A; w2b[i] = -2.f * w2B;
  }
  if (threadIdx.x < C) bs[threadIdx.x] = bias[threadIdx.x] + bias[C + threadIdx.x];
  __syncthreads();
  int n = tid >> 5, s = tid & 31;
  int l0 = 2 * g, l1 = 2 * g + 1;
  const int* rp0 = CSR_RP(csrBase, l0); const int* cs0 = CSR_SRC(csrBase, l0);
  const float* cn0 = CSR_NRM(csrBase, l0);
  const int* rp1 = CSR_RP(csrBase, l1); const int* cs1 = CSR_SRC(csrBase, l1);
  const float* cn1 = CSR_NRM(csrBase, l1);
  const __half* T1a = T1hAll + (size_t)l0 * (NN * 512);
  const __half* T1b = T1hAll + (size_t)l1 * (NN * 512);
  const float4* A4 = reinterpret_cast<const float4*>(T1a);
  const float2* A2 = reinterpret_cast<const float2*>(T1a);
  const float4* B4 = reinterpret_cast<const float4*>(T1b);
  const float2* B2 = reinterpret_cast<const float2*>(T1b);
  float acc0[12], acc1[12];
#pragma unroll
  for (int c = 0; c < 12; ++c) { acc0[c] = 0.f; acc1[c] = 0.f; }
  for (int e = rp0[n], end = rp0[n + 1]; e < end; ++e) {
    float nm = cn0[e];
    long src = cs0[e];
    float f[12];
    unpack8(A4[src * 64 + s * 2], f);
    unpack4(A2[src * 128 + s * 4 + 2], f + 8);
#pragma unroll
    for (int c = 0; c < 12; ++c) acc0[c] += nm * f[c];
  }
  for (int e = rp1[n], end = rp1[n + 1]; e < end; ++e) {
    float nm = cn1[e];
    long src = cs1[e];
    float f[12];
    unpack8(B4[src * 64 + s * 2], f);
    unpack4(B2[src * 128 + s * 4 + 2], f + 8);
#pragma unroll
    for (int c = 0; c < 12; ++c) acc1[c] += nm * f[c];
  }
  float x0[12], ta[12], tb[12];
  {
    const float4* X4 = reinterpret_cast<const float4*>(Xh);
    const float2* X2 = reinterpret_cast<const float2*>(Xh);
    unpack8(X4[(long)tid * 2], x0);     unpack4(X2[(long)tid * 4 + 2], x0 + 8);
    unpack8(A4[(long)tid * 2], ta);     unpack4(A2[(long)tid * 4 + 2], ta + 8);
    unpack8(B4[(long)tid * 2], tb);     unpack4(B2[(long)tid * 4 + 2], tb + 8);
  }
  float z[12];
#pragma unroll
  for (int d = 0; d < C; ++d) {
    float zz = bs[d];
#pragma unroll
    for (int c = 0; c < C; ++c)
      zz += x0[c] * wx[c * C + d] + ta[c] * w1a[c * C + d] + tb[c] * w1b[c * C + d] +
            acc0[c] * w2a[c * C + d] + acc1[c] * w2b[c * C + d];
    z[d] = zz;
  }
  z[11] = 0.f;
  float4* o4 = reinterpret_cast<float4*>(g ? outT : outH) + (long)tid * 3;
  o4[0] = make_float4(z[0], z[1], z[2], z[3]);
  o4[1] = make_float4(z[4], z[5], z[6], z[7]);
  o4[2] = make_float4(z[8], z[9], z[10], 0.f);
}

// ---------------- final: out[r,:] = z[r,:44] @ W[44,128] + bias (fp32 inputs [N][32][12]) ----------------
__global__ __launch_bounds__(256) void final_kernel(const float* __restrict__ H2, const float* __restrict__ T2b,
                                                    const float* __restrict__ W, const float* __restrict__ bias,
                                                    float* __restrict__ out) {
  __shared__ float zsr[64][48];
  int tid = threadIdx.x;
  long r0 = (long)blockIdx.x * 64;
#pragma unroll
  for (int it = 0; it < 3; ++it) {
    int item = it * 256 + tid;          // 768 items = 64 rows x 12 float4
    int row = item / 12, piece = item - row * 12;
    long r = r0 + row;
    int b = (int)(r / NN), n = (int)(r - (long)b * NN);
    const float4* srcb = reinterpret_cast<const float4*>(piece < 6 ? H2 : T2b);
    int f4i = (piece < 6) ? piece : piece - 6;
    float4 v = srcb[((long)n * 32 + b * 2) * 3 + f4i];
    *reinterpret_cast<float4*>(&zsr[row][(piece < 6 ? 0 : 24) + f4i * 4]) = v;
  }
  int c = tid & 127, h = tid >> 7;
  float wp[48];
#pragma unroll
  for (int off = 0; off < 48; ++off) {
    int half_ = off / 24, r_ = off - half_ * 24;
    int t = r_ / 12, c_ = r_ - t * 12;
    wp[off] = (c_ == 11) ? 0.f : W[(2 * (c_ + half_ * 11) + t) * 128 + c];
  }
  float bh = bias[c];
  __syncthreads();
  int rbeg = h * 32;
#pragma unroll 2
  for (int row = rbeg; row < rbeg + 32; ++row) {
    const float4* zr4 = reinterpret_cast<const float4*>(&zsr[row][0]);
    float acc = bh;
#pragma unroll
    for (int q = 0; q < 12; ++q) {
      float4 zv = zr4[q];
      acc = fmaf(zv.x, wp[4 * q + 0], acc);
      acc = fmaf(zv.y, wp[4 * q + 1], acc);
      acc = fmaf(zv.z, wp[4 * q + 2], acc);
      acc = fmaf(zv.w, wp[4 * q + 3], acc);
    }
    out[(r0 + row) * 128 + c] = acc;
  }
}

extern "C" void kernel_launch(void* const* d_in, const int* in_sizes, int n_in,
                              void* d_out, int out_size, void* d_ws, size_t ws_size,
                              hipStream_t stream) {
  const float* x    = (const float*)d_in[0];
  const int*   hg   = (const int*)d_in[1];
  const int*   tg   = (const int*)d_in[2];
  const float* t1w  = (const float*)d_in[3];
  const float* t1b  = (const float*)d_in[4];
  const float* h1W  = (const float*)d_in[5];
  const float* h1b  = (const float*)d_in[6];
  const float* g1W  = (const float*)d_in[7];
  const float* g1b  = (const float*)d_in[8];
  const float* a2w  = (const float*)d_in[9];
  const float* a2b  = (const float*)d_in[10];
  const float* t2w  = (const float*)d_in[11];
  const float* t2b  = (const float*)d_in[12];
  const float* h2W  = (const float*)d_in[13];
  const float* h2b  = (const float*)d_in[14];
  const float* g2W  = (const float*)d_in[15];
  const float* g2b  = (const float*)d_in[16];
  const float* outw = (const float*)d_in[17];
  const float* outb = (const float*)d_in[18];
  float* out = (float*)d_out;

  // workspace layout (halfs: slot = 15,360,000 halfs = 30.72 MB)
  __half* T1h = (__half*)d_ws;               // 4 slots (one per edge list)
  __half* X1h = T1h + 4u * 15360000;         // X1 [N][64][8] -> later X2nh [N][32][16]
  __half* Cfh = X1h + 15360000;              // block1 out (hg)
  __half* Dfh = Cfh + 15360000;              // block1 out (tg)
  float*  Cf  = (float*)(Dfh + 15360000);    // block2 out (hg) [N][32][12] fp32
  float*  Df  = Cf + 11520000;               // block2 out (tg)
  int* csrBase  = (int*)(Df + 11520000);     // 4 * CSR_STRIDE ints
  // CSR-build scratch aliased into Cf (dead until cheb2 writes it)
  int* degO     = (int*)Cf;                  // 4*NN
  int* degI     = degO + 4 * NN;             // 4*NN
  int* cursor   = degI + 4 * NN;             // 4*NN
  int* partials = cursor + 4 * NN;           // 4*NCH

  // --- build CSR (sorted by dst) + norms for all 4 edge lists, batched ---
  hipMemsetAsync(degO, 0, 8 * NN * sizeof(int), stream);
  count_all_kernel<<<(4 * EDGES + 255) / 256, 256, 0, stream>>>(hg, tg, degO, degI);
  scan1_kernel<<<4 * NCH, 256, 0, stream>>>(degI, csrBase, partials);
  scan2_kernel<<<1, 128, 0, stream>>>(partials);
  fixup_kernel<<<4 * NCH, 256, 0, stream>>>(csrBase, cursor, partials);
  fill_all_kernel<<<(4 * EDGES + 255) / 256, 256, 0, stream>>>(hg, tg, degO, degI, cursor, csrBase);

  // --- block1 ---
  glu1_kernel<<<NN * 64 / 256, 256, 0, stream>>>(x, t1w, t1b, X1h);
  pull_all_kernel<<<4 * NN * 64 / 256, 256, 0, stream>>>(csrBase, X1h, T1h);
  cheb1_kernel<<<2 * NN * 64 / 256, 256, 0, stream>>>(csrBase, X1h, T1h, h1W, h1b, g1W, g1b, Cfh, Dfh);

  // --- block2 ---
  glu2_kernel<<<NN * 32 / 256, 256, 0, stream>>>(Cfh, Dfh, t2w, t2b, a2w, a2b, X1h);
  pull_all_kernel<<<4 * NN * 64 / 256, 256, 0, stream>>>(csrBase, X1h, T1h);
  cheb2_kernel<<<2 * NN * 32 / 256, 256, 0, stream>>>(csrBase, X1h, T1h, h2W, h2b, g2W, g2b, Cf, Df);

  // --- final linear ---
  final_kernel<<<7500, 256, 0, stream>>>(Cf, Df, outw, outb, out);
}

// Round 6
// 831.062 us; speedup vs baseline: 14.5256x; 1.0730x over previous
//
#include <hip/hip_runtime.h>
#include <hip/hip_fp16.h>
#include <math.h>

#define EDGES 120000
#define NN    30000
#define NCH   118   // ceil(30000/256)
#define T1SLOT 15360000   // halfs per T1 slot

__device__ __forceinline__ float sigmoidf_(float x) { return 1.f / (1.f + __expf(-x)); }

union F4H8 { float4 v; __half h[8]; };
union F2H4 { float2 v; __half h[4]; };

__device__ __forceinline__ void unpack8(float4 v, float* f) {
  F4H8 u; u.v = v;
#pragma unroll
  for (int i = 0; i < 8; ++i) f[i] = __half2float(u.h[i]);
}
__device__ __forceinline__ float4 pack8(const float* f) {
  F4H8 u;
#pragma unroll
  for (int i = 0; i < 8; ++i) u.h[i] = __float2half(f[i]);
  return u.v;
}
__device__ __forceinline__ void unpack4(float2 v, float* f) {
  F2H4 u; u.v = v;
#pragma unroll
  for (int i = 0; i < 4; ++i) f[i] = __half2float(u.h[i]);
}
__device__ __forceinline__ float2 pack4(const float* f) {
  F2H4 u;
#pragma unroll
  for (int i = 0; i < 4; ++i) u.h[i] = __float2half(f[i]);
  return u.v;
}

// CSR slot layout (ints): rowptr[30016] | pack int2[120000] (src, norm-bits)
#define CSR_STRIDE 270016
#define CSR_RP(base, l)   ((base) + (size_t)(l) * CSR_STRIDE)
#define CSR_PK(base, l)   ((const int2*)((base) + (size_t)(l) * CSR_STRIDE + 30016))
#define CSR_PKW(base, l)  ((int2*)((base) + (size_t)(l) * CSR_STRIDE + 30016))

// ---------------- CSR build ----------------
__global__ void count_all_kernel(const int* __restrict__ hg, const int* __restrict__ tg,
                                 int* __restrict__ degO, int* __restrict__ degI) {
  int tid = blockIdx.x * blockDim.x + threadIdx.x;
  if (tid >= 4 * EDGES) return;
  int l = tid / EDGES, j = tid - l * EDGES;
  const int* G = (l < 2) ? hg : tg;
  const int* src = G + (size_t)(l & 1) * 2 * EDGES;
  const int* dst = src + EDGES;
  atomicAdd(&degO[l * NN + src[j]], 1);
  atomicAdd(&degI[l * NN + dst[j]], 1);
}

__global__ __launch_bounds__(256) void scan1_kernel(const int* __restrict__ degI,
                                                    int* __restrict__ csrBase,
                                                    int* __restrict__ partials) {
  int l = blockIdx.x / NCH, ch = blockIdx.x - l * NCH;
  int tid = threadIdx.x;
  int i = ch * 256 + tid;
  __shared__ int buf[256];
  int v = (i < NN) ? degI[l * NN + i] : 0;
  buf[tid] = v;
  __syncthreads();
  for (int off = 1; off < 256; off <<= 1) {
    int t = (tid >= off) ? buf[tid - off] : 0;
    __syncthreads();
    buf[tid] += t;
    __syncthreads();
  }
  int* rp = CSR_RP(csrBase, l);
  if (i < NN) rp[i + 1] = buf[tid];
  if (tid == 255) partials[l * NCH + ch] = buf[255];
}

__global__ __launch_bounds__(128) void scan2_kernel(int* __restrict__ partials) {
  __shared__ int buf[128];
  int tid = threadIdx.x;
  for (int l = 0; l < 4; ++l) {
    int v = (tid < NCH) ? partials[l * NCH + tid] : 0;
    buf[tid] = v;
    __syncthreads();
    for (int off = 1; off < 128; off <<= 1) {
      int t = (tid >= off) ? buf[tid - off] : 0;
      __syncthreads();
      buf[tid] += t;
      __syncthreads();
    }
    if (tid < NCH) partials[l * NCH + tid] = buf[tid] - v;  // exclusive
    __syncthreads();
  }
}

__global__ __launch_bounds__(256) void fixup_kernel(int* __restrict__ csrBase,
                                                    int* __restrict__ cursor,
                                                    const int* __restrict__ partials) {
  int l = blockIdx.x / NCH, ch = blockIdx.x - l * NCH;
  int i = ch * 256 + threadIdx.x;
  int* rp = CSR_RP(csrBase, l);
  int off = partials[l * NCH + ch];
  if (i < NN) {
    int val = rp[i + 1] + off;
    rp[i + 1] = val;
    if (i + 1 < NN) cursor[l * NN + i + 1] = val;
  }
  if (i == 0) { rp[0] = 0; cursor[l * NN] = 0; }
}

__global__ void fill_all_kernel(const int* __restrict__ hg, const int* __restrict__ tg,
                                const int* __restrict__ degO, const int* __restrict__ degI,
                                int* __restrict__ cursor, int* __restrict__ csrBase) {
  int tid = blockIdx.x * blockDim.x + threadIdx.x;
  if (tid >= 4 * EDGES) return;
  int l = tid / EDGES, j = tid - l * EDGES;
  const int* G = (l < 2) ? hg : tg;
  const int* src = G + (size_t)(l & 1) * 2 * EDGES;
  const int* dst = src + EDGES;
  int s = src[j], d = dst[j];
  int doo = degO[l * NN + s]; if (doo < 1) doo = 1;
  int dii = degI[l * NN + d]; if (dii < 1) dii = 1;
  float nm = rsqrtf((float)doo) * rsqrtf((float)dii);
  int p = atomicAdd(&cursor[l * NN + d], 1);
  CSR_PKW(csrBase, l)[p] = make_int2(s, __float_as_int(nm));
}

// ---------------- block1 temporal GLU conv: x[B,N,6,1] -> X1h [N][64][8] fp16 ----------------
__global__ void glu1_kernel(const float* __restrict__ x, const float* __restrict__ w,
                            const float* __restrict__ b, __half* __restrict__ X1h) {
  int idx = blockIdx.x * blockDim.x + threadIdx.x;   // idx = n*64 + s, s = b*4 + t
  if (idx >= NN * 64) return;
  int n = idx >> 6, s = idx & 63;
  int bb = s >> 2, t = s & 3;
  const float* xb = x + ((long)bb * NN + n) * 6;
  float x0 = xb[t], x1 = xb[t + 1], x2 = xb[t + 2];
  float o[8];
#pragma unroll
  for (int c = 0; c < 8; ++c) {
    float p = w[c * 3 + 0] * x0 + w[c * 3 + 1] * x1 + w[c * 3 + 2] * x2 + b[c];
    float q = w[(c + 8) * 3 + 0] * x0 + w[(c + 8) * 3 + 1] * x1 + w[(c + 8) * 3 + 2] * x2 + b[c + 8];
    float al = (c == 0) ? x2 : 0.f;
    o[c] = (p + al) * sigmoidf_(q);
  }
  reinterpret_cast<float4*>(X1h)[idx] = pack8(o);
}

// ---------------- block1 pull (all 4 lists, 1KB rows, float4 slices, unroll-4) ----------------
__global__ __launch_bounds__(256) void pull1_kernel(const int* __restrict__ csrBase,
                                                    const __half* __restrict__ Xh,
                                                    __half* __restrict__ T1hAll) {
  int gtid = blockIdx.x * 256 + threadIdx.x;
  int l = gtid / (NN * 64);
  int t = gtid - l * (NN * 64);
  int n = t >> 6, j = t & 63;
  const int* rp = CSR_RP(csrBase, l);
  const int2* pk = CSR_PK(csrBase, l);
  const float4* in4 = reinterpret_cast<const float4*>(Xh);
  float acc[8];
#pragma unroll
  for (int i = 0; i < 8; ++i) acc[i] = 0.f;
  int e = rp[n], end = rp[n + 1];
  for (; e + 4 <= end; e += 4) {
    int2 p0 = pk[e], p1 = pk[e + 1], p2 = pk[e + 2], p3 = pk[e + 3];
    float4 v0 = in4[(long)p0.x * 64 + j];
    float4 v1 = in4[(long)p1.x * 64 + j];
    float4 v2 = in4[(long)p2.x * 64 + j];
    float4 v3 = in4[(long)p3.x * 64 + j];
    float f[8];
    float n0 = __int_as_float(p0.y), n1 = __int_as_float(p1.y);
    float n2 = __int_as_float(p2.y), n3 = __int_as_float(p3.y);
    unpack8(v0, f);
#pragma unroll
    for (int i = 0; i < 8; ++i) acc[i] -= n0 * f[i];
    unpack8(v1, f);
#pragma unroll
    for (int i = 0; i < 8; ++i) acc[i] -= n1 * f[i];
    unpack8(v2, f);
#pragma unroll
    for (int i = 0; i < 8; ++i) acc[i] -= n2 * f[i];
    unpack8(v3, f);
#pragma unroll
    for (int i = 0; i < 8; ++i) acc[i] -= n3 * f[i];
  }
  for (; e < end; ++e) {
    int2 p = pk[e];
    float4 v = in4[(long)p.x * 64 + j];
    float nm = __int_as_float(p.y);
    float f[8];
    unpack8(v, f);
#pragma unroll
    for (int i = 0; i < 8; ++i) acc[i] -= nm * f[i];
  }
  reinterpret_cast<float4*>(T1hAll)[(size_t)l * (T1SLOT / 8) + t] = pack8(acc);
}

// ---------------- block1 fused Cheb combine (both graphs, unroll-2 gather) ----------------
__global__ __launch_bounds__(256) void cheb1_kernel(const int* __restrict__ csrBase,
    const __half* __restrict__ Xh, const __half* __restrict__ T1hAll,
    const float* __restrict__ Whg, const float* __restrict__ bhg,
    const float* __restrict__ Wtg, const float* __restrict__ btg,
    __half* __restrict__ outH, __half* __restrict__ outT) {
  constexpr int C = 8, CC = 64;
  __shared__ float wx[CC], w1a[CC], w1b[CC], w2a[CC], w2b[CC], bs[C];
  int gtid = blockIdx.x * 256 + threadIdx.x;
  int g = gtid / (NN * 64);
  int tid = gtid - g * (NN * 64);
  const float* W = g ? Wtg : Whg;
  const float* bias = g ? btg : bhg;
  for (int i = threadIdx.x; i < CC; i += 256) {
    float w0A = W[i], w1A = W[CC + i], w2A = W[2 * CC + i];
    float w0B = W[3 * CC + i], w1B = W[4 * CC + i], w2B = W[5 * CC + i];
    wx[i] = w0A - w2A + w0B - w2B;
    w1a[i] = w1A; w1b[i] = w1B;
    w2a[i] = -2.f * w2A; w2b[i] = -2.f * w2B;
  }
  if (threadIdx.x < C) bs[threadIdx.x] = bias[threadIdx.x] + bias[C + threadIdx.x];
  __syncthreads();
  int n = tid >> 6, s = tid & 63;
  int l0 = 2 * g, l1 = 2 * g + 1;
  const int* rp0 = CSR_RP(csrBase, l0); const int2* pk0 = CSR_PK(csrBase, l0);
  const int* rp1 = CSR_RP(csrBase, l1); const int2* pk1 = CSR_PK(csrBase, l1);
  const float4* A4 = reinterpret_cast<const float4*>(T1hAll + (size_t)l0 * T1SLOT);
  const float4* B4 = reinterpret_cast<const float4*>(T1hAll + (size_t)l1 * T1SLOT);
  float acc0[C], acc1[C];
#pragma unroll
  for (int c = 0; c < C; ++c) { acc0[c] = 0.f; acc1[c] = 0.f; }
  {
    int e = rp0[n], end = rp0[n + 1];
    for (; e + 2 <= end; e += 2) {
      int2 p0 = pk0[e], p1 = pk0[e + 1];
      float4 v0 = A4[(long)p0.x * 64 + s];
      float4 v1 = A4[(long)p1.x * 64 + s];
      float n0 = __int_as_float(p0.y), n1 = __int_as_float(p1.y);
      float f0[8], f1[8];
      unpack8(v0, f0); unpack8(v1, f1);
#pragma unroll
      for (int c = 0; c < C; ++c) acc0[c] += n0 * f0[c] + n1 * f1[c];
    }
    for (; e < end; ++e) {
      int2 p = pk0[e];
      float4 v = A4[(long)p.x * 64 + s];
      float nm = __int_as_float(p.y);
      float f[8]; unpack8(v, f);
#pragma unroll
      for (int c = 0; c < C; ++c) acc0[c] += nm * f[c];
    }
  }
  {
    int e = rp1[n], end = rp1[n + 1];
    for (; e + 2 <= end; e += 2) {
      int2 p0 = pk1[e], p1 = pk1[e + 1];
      float4 v0 = B4[(long)p0.x * 64 + s];
      float4 v1 = B4[(long)p1.x * 64 + s];
      float n0 = __int_as_float(p0.y), n1 = __int_as_float(p1.y);
      float f0[8], f1[8];
      unpack8(v0, f0); unpack8(v1, f1);
#pragma unroll
      for (int c = 0; c < C; ++c) acc1[c] += n0 * f0[c] + n1 * f1[c];
    }
    for (; e < end; ++e) {
      int2 p = pk1[e];
      float4 v = B4[(long)p.x * 64 + s];
      float nm = __int_as_float(p.y);
      float f[8]; unpack8(v, f);
#pragma unroll
      for (int c = 0; c < C; ++c) acc1[c] += nm * f[c];
    }
  }
  float z[C];
#pragma unroll
  for (int d = 0; d < C; ++d) z[d] = bs[d];
  {
    float xv[8], av[8], bv[8];
    unpack8(reinterpret_cast<const float4*>(Xh)[tid], xv);
    unpack8(A4[tid], av);
    unpack8(B4[tid], bv);
#pragma unroll
    for (int c = 0; c < C; ++c) {
      float x0c = xv[c], tac = av[c], tbc = bv[c], a0 = acc0[c], a1 = acc1[c];
#pragma unroll
      for (int d = 0; d < C; ++d)
        z[d] += x0c * wx[c * C + d] + tac * w1a[c * C + d] + tbc * w1b[c * C + d] +
                a0 * w2a[c * C + d] + a1 * w2b[c * C + d];
    }
  }
  reinterpret_cast<float4*>(g ? outT : outH)[tid] = pack8(z);
}

// ---------------- block2 align(1x1)+GLU: Cfh/Dfh [N][64][8] fp16 -> X2nh [N][32][12] fp16 ----------------
__global__ __launch_bounds__(256) void glu2_kernel(const __half* __restrict__ H, const __half* __restrict__ Tt,
                                                   const float* __restrict__ w2, const float* __restrict__ b2,
                                                   const float* __restrict__ aw, const float* __restrict__ ab,
                                                   __half* __restrict__ X2nh) {
  __shared__ float w2s[22 * 16 * 3], b2s[22], aws[11 * 16], abs_[11];
  for (int i = threadIdx.x; i < 22 * 16 * 3; i += 256) w2s[i] = w2[i];
  if (threadIdx.x < 22) b2s[threadIdx.x] = b2[threadIdx.x];
  for (int i = threadIdx.x; i < 11 * 16; i += 256) aws[i] = aw[i];
  if (threadIdx.x < 11) abs_[threadIdx.x] = ab[threadIdx.x];
  __syncthreads();
  int idx = blockIdx.x * 256 + threadIdx.x;   // idx = n*32 + s2, s2 = b*2 + t
  int n = idx >> 5, s = idx & 31;
  int bb = s >> 1, t = s & 1;
  long rbase = (long)n * 64 + bb * 4 + t;     // float4 row index (8 halfs per slice)
  const float4* H4 = reinterpret_cast<const float4*>(H) + rbase;
  const float4* T4 = reinterpret_cast<const float4*>(Tt) + rbase;
  float hv[24], tv[24];
  unpack8(H4[0], hv); unpack8(H4[1], hv + 8); unpack8(H4[2], hv + 16);
  unpack8(T4[0], tv); unpack8(T4[1], tv + 8); unpack8(T4[2], tv + 16);
  float o[12];
  o[11] = 0.f;
#pragma unroll
  for (int co = 0; co < 11; ++co) {
    float p = b2s[co], q = b2s[co + 11], a = abs_[co];
#pragma unroll
    for (int ci = 0; ci < 16; ++ci) {
      float v0 = (ci < 8) ? hv[ci] : tv[ci - 8];
      float v1 = (ci < 8) ? hv[8 + ci] : tv[ci];
      float v2 = (ci < 8) ? hv[16 + ci] : tv[8 + ci];
      p += w2s[(co * 16 + ci) * 3 + 0] * v0 + w2s[(co * 16 + ci) * 3 + 1] * v1 +
           w2s[(co * 16 + ci) * 3 + 2] * v2;
      q += w2s[((co + 11) * 16 + ci) * 3 + 0] * v0 + w2s[((co + 11) * 16 + ci) * 3 + 1] * v1 +
           w2s[((co + 11) * 16 + ci) * 3 + 2] * v2;
      a += aws[co * 16 + ci] * v2;
    }
    o[co] = (p + a) * sigmoidf_(q);
  }
  float2* o2 = reinterpret_cast<float2*>(X2nh) + (long)idx * 3;
  o2[0] = pack4(o);
  o2[1] = pack4(o + 4);
  o2[2] = pack4(o + 8);
}

// ---------------- block2 pull (all 4 lists, 768B rows, float2 slices, unroll-4) ----------------
__global__ __launch_bounds__(256) void pull2_kernel(const int* __restrict__ csrBase,
                                                    const __half* __restrict__ Xh,
                                                    __half* __restrict__ T1hAll) {
  int gtid = blockIdx.x * 256 + threadIdx.x;
  int l = gtid / (NN * 96);
  int t = gtid - l * (NN * 96);
  int n = t / 96, j = t - n * 96;
  const int* rp = CSR_RP(csrBase, l);
  const int2* pk = CSR_PK(csrBase, l);
  const float2* in2 = reinterpret_cast<const float2*>(Xh);
  float acc[4];
#pragma unroll
  for (int i = 0; i < 4; ++i) acc[i] = 0.f;
  int e = rp[n], end = rp[n + 1];
  for (; e + 4 <= end; e += 4) {
    int2 p0 = pk[e], p1 = pk[e + 1], p2 = pk[e + 2], p3 = pk[e + 3];
    float2 v0 = in2[(long)p0.x * 96 + j];
    float2 v1 = in2[(long)p1.x * 96 + j];
    float2 v2 = in2[(long)p2.x * 96 + j];
    float2 v3 = in2[(long)p3.x * 96 + j];
    float f[4];
    float n0 = __int_as_float(p0.y), n1 = __int_as_float(p1.y);
    float n2 = __int_as_float(p2.y), n3 = __int_as_float(p3.y);
    unpack4(v0, f);
#pragma unroll
    for (int i = 0; i < 4; ++i) acc[i] -= n0 * f[i];
    unpack4(v1, f);
#pragma unroll
    for (int i = 0; i < 4; ++i) acc[i] -= n1 * f[i];
    unpack4(v2, f);
#pragma unroll
    for (int i = 0; i < 4; ++i) acc[i] -= n2 * f[i];
    unpack4(v3, f);
#pragma unroll
    for (int i = 0; i < 4; ++i) acc[i] -= n3 * f[i];
  }
  for (; e < end; ++e) {
    int2 p = pk[e];
    float2 v = in2[(long)p.x * 96 + j];
    float nm = __int_as_float(p.y);
    float f[4];
    unpack4(v, f);
#pragma unroll
    for (int i = 0; i < 4; ++i) acc[i] -= nm * f[i];
  }
  reinterpret_cast<float2*>(T1hAll)[(size_t)l * (T1SLOT / 4) + t] = pack4(acc);
}

// ---------------- block2 fused Cheb combine (both graphs, unroll-2 gather, fp16 out) ----------------
__global__ __launch_bounds__(256) void cheb2_kernel(const int* __restrict__ csrBase,
    const __half* __restrict__ Xh, const __half* __restrict__ T1hAll,
    const float* __restrict__ Whg, const float* __restrict__ bhg,
    const float* __restrict__ Wtg, const float* __restrict__ btg,
    __half* __restrict__ outH, __half* __restrict__ outT) {
  constexpr int C = 11, CC = 121;
  __shared__ float wx[CC], w1a[CC], w1b[CC], w2a[CC], w2b[CC], bs[C];
  int gtid = blockIdx.x * 256 + threadIdx.x;
  int g = gtid / (NN * 32);
  int tid = gtid - g * (NN * 32);
  const float* W = g ? Wtg : Whg;
  const float* bias = g ? btg : bhg;
  for (int i = threadIdx.x; i < CC; i += 256) {
    float w0A = W[i], w1A = W[CC + i], w2A = W[2 * CC + i];
    float w0B = W[3 * CC + i], w1B = W[4 * CC + i], w2B = W[5 * CC + i];
    wx[i] = w0A - w2A + w0B - w2B;
    w1a[i] = w1A; w1b[i] = w1B;
    w2a[i] = -2.f * w2A; w2b[i] = -2.f * w2B;
  }
  if (threadIdx.x < C) bs[threadIdx.x] = bias[threadIdx.x] + bias[C + threadIdx.x];
  __syncthreads();
  int n = tid >> 5, s = tid & 31;
  int s3 = s * 3;
  int l0 = 2 * g, l1 = 2 * g + 1;
  const int* rp0 = CSR_RP(csrBase, l0); const int2* pk0 = CSR_PK(csrBase, l0);
  const int* rp1 = CSR_RP(csrBase, l1); const int2* pk1 = CSR_PK(csrBase, l1);
  const float2* A2v = reinterpret_cast<const float2*>(T1hAll + (size_t)l0 * T1SLOT);
  const float2* B2v = reinterpret_cast<const float2*>(T1hAll + (size_t)l1 * T1SLOT);
  float acc0[12], acc1[12];
#pragma unroll
  for (int c = 0; c < 12; ++c) { acc0[c] = 0.f; acc1[c] = 0.f; }
  {
    int e = rp0[n], end = rp0[n + 1];
    for (; e + 2 <= end; e += 2) {
      int2 p0 = pk0[e], p1 = pk0[e + 1];
      long r0 = (long)p0.x * 96 + s3, r1 = (long)p1.x * 96 + s3;
      float2 a0 = A2v[r0], a1 = A2v[r0 + 1], a2 = A2v[r0 + 2];
      float2 b0 = A2v[r1], b1 = A2v[r1 + 1], b2 = A2v[r1 + 2];
      float n0 = __int_as_float(p0.y), n1 = __int_as_float(p1.y);
      float f[4];
      unpack4(a0, f);
#pragma unroll
      for (int i = 0; i < 4; ++i) acc0[i] += n0 * f[i];
      unpack4(a1, f);
#pragma unroll
      for (int i = 0; i < 4; ++i) acc0[4 + i] += n0 * f[i];
      unpack4(a2, f);
#pragma unroll
      for (int i = 0; i < 4; ++i) acc0[8 + i] += n0 * f[i];
      unpack4(b0, f);
#pragma unroll
      for (int i = 0; i < 4; ++i) acc0[i] += n1 * f[i];
      unpack4(b1, f);
#pragma unroll
      for (int i = 0; i < 4; ++i) acc0[4 + i] += n1 * f[i];
      unpack4(b2, f);
#pragma unroll
      for (int i = 0; i < 4; ++i) acc0[8 + i] += n1 * f[i];
    }
    for (; e < end; ++e) {
      int2 p = pk0[e];
      long r = (long)p.x * 96 + s3;
      float2 a0 = A2v[r], a1 = A2v[r + 1], a2 = A2v[r + 2];
      float nm = __int_as_float(p.y);
      float f[4];
      unpack4(a0, f);
#pragma unroll
      for (int i = 0; i < 4; ++i) acc0[i] += nm * f[i];
      unpack4(a1, f);
#pragma unroll
      for (int i = 0; i < 4; ++i) acc0[4 + i] += nm * f[i];
      unpack4(a2, f);
#pragma unroll
      for (int i = 0; i < 4; ++i) acc0[8 + i] += nm * f[i];
    }
  }
  {
    int e = rp1[n], end = rp1[n + 1];
    for (; e + 2 <= end; e += 2) {
      int2 p0 = pk1[e], p1 = pk1[e + 1];
      long r0 = (long)p0.x * 96 + s3, r1 = (long)p1.x * 96 + s3;
      float2 a0 = B2v[r0], a1 = B2v[r0 + 1], a2 = B2v[r0 + 2];
      float2 b0 = B2v[r1], b1 = B2v[r1 + 1], b2 = B2v[r1 + 2];
      float n0 = __int_as_float(p0.y), n1 = __int_as_float(p1.y);
      float f[4];
      unpack4(a0, f);
#pragma unroll
      for (int i = 0; i < 4; ++i) acc1[i] += n0 * f[i];
      unpack4(a1, f);
#pragma unroll
      for (int i = 0; i < 4; ++i) acc1[4 + i] += n0 * f[i];
      unpack4(a2, f);
#pragma unroll
      for (int i = 0; i < 4; ++i) acc1[8 + i] += n0 * f[i];
      unpack4(b0, f);
#pragma unroll
      for (int i = 0; i < 4; ++i) acc1[i] += n1 * f[i];
      unpack4(b1, f);
#pragma unroll
      for (int i = 0; i < 4; ++i) acc1[4 + i] += n1 * f[i];
      unpack4(b2, f);
#pragma unroll
      for (int i = 0; i < 4; ++i) acc1[8 + i] += n1 * f[i];
    }
    for (; e < end; ++e) {
      int2 p = pk1[e];
      long r = (long)p.x * 96 + s3;
      float2 a0 = B2v[r], a1 = B2v[r + 1], a2 = B2v[r + 2];
      float nm = __int_as_float(p.y);
      float f[4];
      unpack4(a0, f);
#pragma unroll
      for (int i = 0; i < 4; ++i) acc1[i] += nm * f[i];
      unpack4(a1, f);
#pragma unroll
      for (int i = 0; i < 4; ++i) acc1[4 + i] += nm * f[i];
      unpack4(a2, f);
#pragma unroll
      for (int i = 0; i < 4; ++i) acc1[8 + i] += nm * f[i];
    }
  }
  // streamed matmul: z[d] = bias + sum_c inputs(c) * weights(c,d)
  float z[12];
#pragma unroll
  for (int d = 0; d < C; ++d) z[d] = bs[d];
  z[11] = 0.f;
  const float2* X2v = reinterpret_cast<const float2*>(Xh);
  long own = (long)tid * 3;
#pragma unroll
  for (int q = 0; q < 3; ++q) {
    float xv[4], av[4], bv[4];
    unpack4(X2v[own + q], xv);
    unpack4(A2v[own + q], av);
    unpack4(B2v[own + q], bv);
#pragma unroll
    for (int k = 0; k < 4; ++k) {
      int c = q * 4 + k;
      if (c == 11) continue;
      float x0c = xv[k], tac = av[k], tbc = bv[k], a0 = acc0[c], a1 = acc1[c];
#pragma unroll
      for (int d = 0; d < C; ++d)
        z[d] += x0c * wx[c * C + d] + tac * w1a[c * C + d] + tbc * w1b[c * C + d] +
                a0 * w2a[c * C + d] + a1 * w2b[c * C + d];
    }
  }
  float2* o2 = reinterpret_cast<float2*>(g ? outT : outH) + (long)tid * 3;
  o2[0] = pack4(z);
  o2[1] = pack4(z + 4);
  o2[2] = pack4(z + 8);
}

// ---------------- final: out[r,:] = z[r,:44] @ W[44,128] + bias (fp16 inputs [N][32][12]) ----------------
__global__ __launch_bounds__(256) void final_kernel(const __half* __restrict__ H2, const __half* __restrict__ T2b,
                                                    const float* __restrict__ W, const float* __restrict__ bias,
                                                    float* __restrict__ out) {
  __shared__ __half zsr[64][48];   // [row][H2-t0(12) H2-t1(12) T2-t0(12) T2-t1(12)]
  int tid = threadIdx.x;
  long r0 = (long)blockIdx.x * 64;
#pragma unroll
  for (int it = 0; it < 2; ++it) {
    int item = it * 256 + tid;          // 384 items = 64 rows x 6 float4 (24 halfs per src)
    if (item < 384) {
      int row = item / 6, piece = item - row * 6;
      long r = r0 + row;
      int b = (int)(r / NN), n = (int)(r - (long)b * NN);
      const float4* srcb = reinterpret_cast<const float4*>(piece < 3 ? H2 : T2b);
      int f4i = (piece < 3) ? piece : piece - 3;
      // 2 adjacent slices (s=b*2, b*2+1) = 24 halfs = 48B contiguous, 16B-aligned
      float4 v = srcb[(long)n * 48 + b * 3 + f4i];
      *reinterpret_cast<float4*>(&zsr[row][(piece < 3 ? 0 : 24) + f4i * 8]) = v;
    }
  }
  int c = tid & 127, h = tid >> 7;
  float wp[48];
#pragma unroll
  for (int off = 0; off < 48; ++off) {
    int half_ = off / 24, r_ = off - half_ * 24;
    int t = r_ / 12, c_ = r_ - t * 12;
    wp[off] = (c_ == 11) ? 0.f : W[(2 * (c_ + half_ * 11) + t) * 128 + c];
  }
  float bh = bias[c];
  __syncthreads();
  int rbeg = h * 32;
#pragma unroll 2
  for (int row = rbeg; row < rbeg + 32; ++row) {
    const float4* zr4 = reinterpret_cast<const float4*>(&zsr[row][0]);
    float acc = bh;
#pragma unroll
    for (int q = 0; q < 6; ++q) {
      F4H8 u; u.v = zr4[q];
#pragma unroll
      for (int i = 0; i < 8; ++i)
        acc = fmaf(__half2float(u.h[i]), wp[q * 8 + i], acc);
    }
    out[(r0 + row) * 128 + c] = acc;
  }
}

extern "C" void kernel_launch(void* const* d_in, const int* in_sizes, int n_in,
                              void* d_out, int out_size, void* d_ws, size_t ws_size,
                              hipStream_t stream) {
  const float* x    = (const float*)d_in[0];
  const int*   hg   = (const int*)d_in[1];
  const int*   tg   = (const int*)d_in[2];
  const float* t1w  = (const float*)d_in[3];
  const float* t1b  = (const float*)d_in[4];
  const float* h1W  = (const float*)d_in[5];
  const float* h1b  = (const float*)d_in[6];
  const float* g1W  = (const float*)d_in[7];
  const float* g1b  = (const float*)d_in[8];
  const float* a2w  = (const float*)d_in[9];
  const float* a2b  = (const float*)d_in[10];
  const float* t2w  = (const float*)d_in[11];
  const float* t2b  = (const float*)d_in[12];
  const float* h2W  = (const float*)d_in[13];
  const float* h2b  = (const float*)d_in[14];
  const float* g2W  = (const float*)d_in[15];
  const float* g2b  = (const float*)d_in[16];
  const float* outw = (const float*)d_in[17];
  const float* outb = (const float*)d_in[18];
  float* out = (float*)d_out;

  // workspace layout
  __half* T1h = (__half*)d_ws;                 // 4 slots x 15,360,000 halfs
  __half* Xh  = T1h + 4L * T1SLOT;             // X1 [N][64][8] -> X2n [N][32][12]
  __half* Cfh = Xh + T1SLOT;                   // block1 H out -> block2 H out
  __half* Dfh = Cfh + T1SLOT;                  // block1 T out -> block2 T out
  int* csrBase  = (int*)(Dfh + T1SLOT);        // 4 * CSR_STRIDE ints
  int* degO     = csrBase + 4 * CSR_STRIDE;    // 4*NN
  int* degI     = degO + 4 * NN;               // 4*NN
  int* cursor   = degI + 4 * NN;               // 4*NN
  int* partials = cursor + 4 * NN;             // 4*NCH

  // --- build CSR (sorted by dst) + norms for all 4 edge lists, batched ---
  hipMemsetAsync(degO, 0, 8 * NN * sizeof(int), stream);
  count_all_kernel<<<(4 * EDGES + 255) / 256, 256, 0, stream>>>(hg, tg, degO, degI);
  scan1_kernel<<<4 * NCH, 256, 0, stream>>>(degI, csrBase, partials);
  scan2_kernel<<<1, 128, 0, stream>>>(partials);
  fixup_kernel<<<4 * NCH, 256, 0, stream>>>(csrBase, cursor, partials);
  fill_all_kernel<<<(4 * EDGES + 255) / 256, 256, 0, stream>>>(hg, tg, degO, degI, cursor, csrBase);

  // --- block1 ---
  glu1_kernel<<<NN * 64 / 256, 256, 0, stream>>>(x, t1w, t1b, Xh);
  pull1_kernel<<<4 * NN * 64 / 256, 256, 0, stream>>>(csrBase, Xh, T1h);
  cheb1_kernel<<<2 * NN * 64 / 256, 256, 0, stream>>>(csrBase, Xh, T1h, h1W, h1b, g1W, g1b, Cfh, Dfh);

  // --- block2 ---
  glu2_kernel<<<NN * 32 / 256, 256, 0, stream>>>(Cfh, Dfh, t2w, t2b, a2w, a2b, Xh);
  pull2_kernel<<<4 * NN * 96 / 256, 256, 0, stream>>>(csrBase, Xh, T1h);
  cheb2_kernel<<<2 * NN * 32 / 256, 256, 0, stream>>>(csrBase, Xh, T1h, h2W, h2b, g2W, g2b, Cfh, Dfh);

  // --- final linear ---
  final_kernel<<<7500, 256, 0, stream>>>(Cfh, Dfh, outw, outb, out);
}